// Round 1
// baseline (223849.243 us; speedup 1.0000x reference)
//
#include <hip/hip_runtime.h>

#define SS 500
#define NBLKS 256

typedef __bf16 bf16_t;
typedef bf16_t bf16x8 __attribute__((ext_vector_type(8)));
typedef float floatx4 __attribute__((ext_vector_type(4)));

union ABu { uint4 u4; bf16x8 v; unsigned short us[8]; };

#define MFMA(a,b,c) __builtin_amdgcn_mfma_f32_16x16x32_bf16((a),(b),(c),0,0,0)

__device__ __forceinline__ float b2f(unsigned short u){
  union { unsigned int ui; float f; } x; x.ui = ((unsigned int)u) << 16; return x.f;
}
__device__ __forceinline__ unsigned short f2b(float f){
  union { float f; unsigned int ui; } x; x.f = f;
  unsigned int r = x.ui + 0x7FFFu + ((x.ui >> 16) & 1u);
  return (unsigned short)(r >> 16);
}
__device__ __forceinline__ float sigf(float x){ return 1.f/(1.f + __expf(-x)); }
__device__ __forceinline__ float tanhf_fast(float x){
  x = fminf(fmaxf(x, -15.f), 15.f);
  float e = __expf(2.f*x);
  return (e - 1.f)/(e + 1.f);
}

__device__ __forceinline__ void gbar(unsigned int* cnt, unsigned int target){
  __syncthreads();
  if (threadIdx.x == 0){
    __hip_atomic_fetch_add(cnt, 1u, __ATOMIC_RELEASE, __HIP_MEMORY_SCOPE_AGENT);
    while (__hip_atomic_load(cnt, __ATOMIC_ACQUIRE, __HIP_MEMORY_SCOPE_AGENT) < target)
      __builtin_amdgcn_s_sleep(2);
  }
  __syncthreads();
}

// ---------------- prep kernels ----------------

// pm[b][t][h] = enc[b,t,:]@encW[h,:] + encB[h]   (bf16 store)
__global__ void k_pm(const float* __restrict__ enc, const float* __restrict__ ew,
                     const float* __restrict__ eb, unsigned short* __restrict__ pmb){
  int id = blockIdx.x*256 + threadIdx.x;
  if (id >= 64*200*128) return;
  int h = id & 127; int bt = id >> 7;
  const float* er = enc + (size_t)bt*256;
  const float* wr = ew + (size_t)h*256;
  float a0=eb[h], a1=0.f, a2=0.f, a3=0.f;
  for (int k=0;k<256;k+=4){
    a0 += er[k]*wr[k]; a1 += er[k+1]*wr[k+1]; a2 += er[k+2]*wr[k+2]; a3 += er[k+3]*wr[k+3];
  }
  pmb[id] = f2b((a0+a1)+(a2+a3));
}

__global__ void k_encb(const float* __restrict__ enc, unsigned short* __restrict__ encb){
  int id = blockIdx.x*256 + threadIdx.x;
  if (id >= 64*200*256) return;
  encb[id] = f2b(enc[id]);
}

// Wdeck[k][h] = att_fc_dec_w[h][k]  (k-major, bf16)
__global__ void k_wdeck(const float* __restrict__ wd, unsigned short* __restrict__ dst){
  int id = blockIdx.x*256 + threadIdx.x;
  if (id >= 1024*128) return;
  int k = id >> 7, h = id & 127;
  dst[id] = f2b(wd[(size_t)h*1024 + k]);
}

// W2[h][k] = sum_c attW[h][c]*convW[c][k]; packed into MFMA B-frags (K padded 31->32)
__global__ void k_w2f(const float* __restrict__ attw, const float* __restrict__ convw,
                      unsigned short* __restrict__ w2f){
  __shared__ float s_w2[128*31];
  int tid = threadIdx.x;
  for (int i = tid; i < 128*31; i += 256){
    int h = i / 31, k = i % 31;
    float v = 0.f;
    for (int c=0;c<32;++c) v += attw[h*32+c]*convw[c*31+k];
    s_w2[i] = v;
  }
  __syncthreads();
  for (int i = tid; i < 512; i += 256){
    int nt = i >> 6, lane = i & 63;
    int h = nt*16 + (lane&15);
    for (int j=0;j<8;++j){
      int k = (lane>>4)*8 + j;
      w2f[(nt*64+lane)*8+j] = f2b(k < 31 ? s_w2[h*31+k] : 0.f);
    }
  }
}

// LSTM weight pack: per-CU slice (8 hidden units = 32 gate rows, 2 n-tiles), B-frag order.
// row = g*1024 + cu*8 + du ; n = nt*16+(lane&15), du=n>>2, g=n&3 ; k<Kih -> wih else whh
__global__ void k_packlstm(const float* __restrict__ wih, const float* __restrict__ whh,
                           unsigned short* __restrict__ dst, int Kih, int NKS){
  int id = blockIdx.x*256 + threadIdx.x;
  if (id >= 128*NKS*64) return;
  int lane = id & 63; int t = id >> 6; int cu = t / NKS;
  for (int nt=0; nt<2; ++nt){
    int n = nt*16 + (lane&15);
    int du = n>>2, g = n&3;
    int row = g*1024 + cu*8 + du;
    for (int j=0;j<8;++j){
      int k = (t % NKS)*32 + ((lane>>4)*8) + j;
      float v = (k < Kih) ? wih[(size_t)row*Kih + k] : whh[(size_t)row*1024 + (k - Kih)];
      dst[((size_t)(t*2+nt)*64 + lane)*8 + j] = f2b(v);
    }
  }
}

__global__ void k_bias(const float* bi0,const float* bh0,const float* bi1,const float* bh1,
                       float* b0p, float* b1p){
  int id = blockIdx.x*256 + threadIdx.x;
  if (id >= 4096) return;
  int cu = id>>5, n = id&31, du = n>>2, g = n&3;
  int row = g*1024 + cu*8 + du;
  b0p[id] = bi0[row] + bh0[row];
  b1p[id] = bi1[row] + bh1[row];
}

// generic B-frag pack of src[N][K] (row-major fp32)
__global__ void k_packgen(const float* __restrict__ src, unsigned short* __restrict__ dst,
                          int N, int K){
  int tot = (N/16)*(K/32)*64;
  int id = blockIdx.x*256 + threadIdx.x;
  if (id >= tot) return;
  int lane = id & 63; int t = id >> 6;
  int nks = K/32;
  int n = (t / nks)*16 + (lane&15);
  for (int j=0;j<8;++j){
    int k = (t % nks)*32 + (lane>>4)*8 + j;
    dst[((size_t)t*64 + lane)*8 + j] = f2b(src[(size_t)n*K + k]);
  }
}

// combined output proj: rows 0..159 feat_out_w, 160..161 prob_out_w, 162..175 zero
__global__ void k_woutp(const float* __restrict__ fw, const float* __restrict__ pw,
                        unsigned short* __restrict__ dst){
  int id = blockIdx.x*256 + threadIdx.x;
  if (id >= 11*40*64) return;
  int lane = id & 63; int t = id >> 6;
  int n = (t/40)*16 + (lane&15);
  for (int j=0;j<8;++j){
    int k = (t%40)*32 + (lane>>4)*8 + j;
    float v = 0.f;
    if (n < 160) v = fw[(size_t)n*1280 + k];
    else if (n < 162) v = pw[(size_t)(n-160)*1280 + k];
    dst[((size_t)t*64 + lane)*8 + j] = f2b(v);
  }
}

// prenet layer1: C1[sb][i] = relu(X[sb]@w0^T + b0), X gathered from feature_target (X=0 for s=0)
__global__ void k_pre1(const float* __restrict__ ftgt, const unsigned short* __restrict__ w0p,
                       const float* __restrict__ b0, unsigned short* __restrict__ C1){
  int mt = blockIdx.x;
  int tid = threadIdx.x, w = tid>>6, L = tid&63, ccol = L&15, q = L>>4;
  int sb0 = mt*16; int s = sb0 >> 6; int b0r = sb0 & 63;
  floatx4 z = {0.f,0.f,0.f,0.f};
  floatx4 acc[4] = {z,z,z,z};
  for (int ks=0; ks<5; ++ks){
    ABu av;
    if (s == 0){ av.u4.x=0; av.u4.y=0; av.u4.z=0; av.u4.w=0; }
    else {
      int b = b0r + ccol;
      for (int j=0;j<8;++j){
        int jj = ks*32 + q*8 + j;
        av.us[j] = f2b(ftgt[(size_t)b*80000 + (size_t)(jj%80)*1000 + (size_t)(s-1)*2 + (jj/80)]);
      }
    }
    for (int i=0;i<4;++i){
      ABu bf; bf.u4 = *(const uint4*)(w0p + ((size_t)((w*4+i)*5 + ks)*64 + L)*8);
      acc[i] = MFMA(av.v, bf.v, acc[i]);
    }
  }
  for (int i=0;i<4;++i){
    int icol = (w*4+i)*16 + ccol;
    float bia = b0[icol];
    for (int r=0;r<4;++r){
      int sb = sb0 + q*4 + r;
      C1[(size_t)sb*256 + icol] = f2b(fmaxf(acc[i][r] + bia, 0.f));
    }
  }
}

// prenet layer2: P = relu(C1@w1^T + b1)
__global__ void k_pre2(const unsigned short* __restrict__ C1, const unsigned short* __restrict__ w1p,
                       const float* __restrict__ b1, unsigned short* __restrict__ P){
  int mt = blockIdx.x;
  int tid = threadIdx.x, w = tid>>6, L = tid&63, ccol = L&15, q = L>>4;
  int sb0 = mt*16;
  floatx4 z = {0.f,0.f,0.f,0.f};
  floatx4 acc[4] = {z,z,z,z};
  for (int ks=0; ks<8; ++ks){
    ABu av; av.u4 = *(const uint4*)(C1 + (size_t)(sb0+ccol)*256 + ks*32 + q*8);
    for (int i=0;i<4;++i){
      ABu bf; bf.u4 = *(const uint4*)(w1p + ((size_t)((w*4+i)*8 + ks)*64 + L)*8);
      acc[i] = MFMA(av.v, bf.v, acc[i]);
    }
  }
  for (int i=0;i<4;++i){
    int icol = (w*4+i)*16 + ccol;
    float bia = b1[icol];
    for (int r=0;r<4;++r){
      int sb = sb0 + q*4 + r;
      P[(size_t)sb*256 + icol] = f2b(fmaxf(acc[i][r] + bia, 0.f));
    }
  }
}

// ---------------- persistent decoder ----------------

struct PArgs {
  const int* tlen;
  const float* ww; const float* wwb; const float* probb;
  const unsigned short* pmb; const unsigned short* encb;
  const unsigned short* W2f; const unsigned short* Wdeck;
  const unsigned short* W0p; const unsigned short* W1p;
  const float* b0p; const float* b1p;
  const unsigned short* P; const unsigned short* Woutp;
  unsigned short* xh0; unsigned short* xh1; unsigned short* acbf;
  unsigned int* bar;
  float* dout;
};

__global__ __launch_bounds__(256, 2) void k_decoder(PArgs A)
{
  const int cu = blockIdx.x;
  const int tid = threadIdx.x;
  const int w = tid>>6, L = tid&63;
  const int ccol = L&15, q = L>>4;

  __shared__ unsigned short s_ahi[240], s_alo[240];
  __shared__ float s_e[256];
  __shared__ float s_red[256];
  __shared__ float s_dp[128];
  __shared__ float s_ww[128];
  __shared__ float s_gb[64*32];
  __shared__ float s_cst[512];
  __shared__ float s_hst[512];
  __shared__ float s_bias[32];

  // ---- init ----
  float accv = 0.f; int lenb = 0; float wwbv = 0.f;
  if (cu < 64) {
    lenb = A.tlen[cu];
    wwbv = A.wwb[0];
    float inv = 1.f / (float)lenb;
    for (int i = tid; i < 240; i += 256) {
      int t = i - 15;
      float v = (t >= 0 && t < 200 && t < lenb) ? inv : 0.f;
      unsigned short hi = f2b(v);
      s_ahi[i] = hi; s_alo[i] = f2b(v - b2f(hi));
    }
    if (tid < 200) accv = (tid < lenb) ? inv : 0.f;
    if (tid < 128) s_ww[tid] = A.ww[tid];
  }
  for (int i = tid; i < 512; i += 256){ s_cst[i] = 0.f; s_hst[i] = 0.f; }
  if (tid < 32){
    s_bias[tid] = (cu < 128) ? A.b0p[cu*32+tid] : A.b1p[(cu-128)*32+tid];
  }
  for (int i = tid; i < 512; i += 256){ A.xh0[cu*512 + i] = 0; A.xh1[cu*512 + i] = 0; }

  unsigned int ep = 0;
  gbar(A.bar, (++ep)*NBLKS);

  for (int s = 0; s <= SS; ++s) {
    // ================= PHASE A =================
    if (cu < 64 && s < SS) {
      const int b = cu;
      const unsigned short* xh0r = A.xh0 + ((s+1)&1)*65536;
      // ---- dec proj dp[h] = h0_{s-1} @ Wdec^T ----
      {
        int h = tid & 127, half = tid >> 7;
        const unsigned short* h0r = xh0r + b*1024 + half*512;
        const unsigned short* wd = A.Wdeck + (size_t)half*512*128 + h;
        float a0=0.f,a1=0.f,a2=0.f,a3=0.f;
        for (int k=0;k<512;k+=4){
          a0 += b2f(h0r[k  ])*b2f(wd[(size_t)(k  )*128]);
          a1 += b2f(h0r[k+1])*b2f(wd[(size_t)(k+1)*128]);
          a2 += b2f(h0r[k+2])*b2f(wd[(size_t)(k+2)*128]);
          a3 += b2f(h0r[k+3])*b2f(wd[(size_t)(k+3)*128]);
        }
        s_red[tid] = (a0+a1)+(a2+a3);
        __syncthreads();
        if (tid < 128) s_dp[tid] = s_red[tid] + s_red[tid+128];
        __syncthreads();
      }
      // ---- conv (MFMA, hi/lo split) + scores ----
      {
        ABu w2f[8];
        for (int nt=0; nt<8; ++nt) w2f[nt].u4 = *(const uint4*)(A.W2f + (nt*64 + L)*8);
        const unsigned short* pmrow = A.pmb + (size_t)b*200*128;
        for (int mt = w; mt < 13; mt += 4) {
          ABu ahi, alo;
          int abase = mt*16 + ccol + q*8;
          for (int j=0;j<8;++j){ ahi.us[j] = s_ahi[abase+j]; alo.us[j] = s_alo[abase+j]; }
          floatx4 acc[8];
          for (int nt=0;nt<8;++nt){
            floatx4 zz = {0.f,0.f,0.f,0.f};
            zz = MFMA(ahi.v, w2f[nt].v, zz);
            zz = MFMA(alo.v, w2f[nt].v, zz);
            acc[nt] = zz;
          }
          for (int r=0;r<4;++r){
            int t = mt*16 + q*4 + r;
            float part = 0.f;
            if (t < 200) {
              for (int nt=0;nt<8;++nt){
                int h = nt*16 + ccol;
                float v = acc[nt][r] + b2f(pmrow[t*128+h]) + s_dp[h];
                part += s_ww[h] * tanhf_fast(v);
              }
            }
            part += __shfl_xor(part, 1);
            part += __shfl_xor(part, 2);
            part += __shfl_xor(part, 4);
            part += __shfl_xor(part, 8);
            if (t < 200 && ccol == 0)
              s_e[t] = (t < lenb) ? (part + wwbv) : -1e30f;
          }
        }
      }
      __syncthreads();
      // ---- softmax + acc update ----
      {
        float v = (tid < 200) ? s_e[tid] : -1e30f;
        s_red[tid] = v; __syncthreads();
        for (int off=128; off>0; off>>=1){
          if (tid < off) s_red[tid] = fmaxf(s_red[tid], s_red[tid+off]);
          __syncthreads();
        }
        float m = s_red[0]; __syncthreads();
        float ex = (tid < 200) ? __expf(v - m) : 0.f;
        s_red[tid] = ex; __syncthreads();
        for (int off=128; off>0; off>>=1){
          if (tid < off) s_red[tid] += s_red[tid+off];
          __syncthreads();
        }
        float inv = 1.f / s_red[0];
        if (tid < 200){
          float aw = ex * inv;
          s_e[tid] = aw;
          A.dout[5184000 + (size_t)b*100000 + (size_t)s*200 + tid] = aw;
          accv = (s == 0) ? aw : (accv + aw);
          unsigned short hi = f2b(accv);
          s_ahi[15+tid] = hi; s_alo[15+tid] = f2b(accv - b2f(hi));
        }
      }
      __syncthreads();
      // ---- ac[c] = sum_t aw[t]*enc[b,t,c] ----
      {
        const unsigned short* er = A.encb + (size_t)b*200*256 + tid;
        float a0=0.f,a1=0.f,a2=0.f,a3=0.f;
        for (int t=0;t<200;t+=4){
          a0 += s_e[t  ]*b2f(er[(size_t)(t  )*256]);
          a1 += s_e[t+1]*b2f(er[(size_t)(t+1)*256]);
          a2 += s_e[t+2]*b2f(er[(size_t)(t+2)*256]);
          a3 += s_e[t+3]*b2f(er[(size_t)(t+3)*256]);
        }
        A.acbf[(s&1)*16384 + b*256 + tid] = f2b((a0+a1)+(a2+a3));
      }
    }
    if (cu >= 128 && s >= 1) {
      // LSTM1 for step s-1
      const int cp = cu - 128;
      const unsigned short* Wp = A.W1p + (size_t)cp*64*2*512;
      const unsigned short* segA = A.xh0 + ((s+1)&1)*65536;   // h0_{s-1}
      const unsigned short* segB = A.xh1 + (s&1)*65536;       // h1_{s-2}
      floatx4 a0 = {0.f,0.f,0.f,0.f}, a1 = {0.f,0.f,0.f,0.f};
      int brow = w*16 + ccol;
      for (int ks=0; ks<64; ++ks){
        const unsigned short* ap = (ks < 32) ? (segA + (size_t)brow*1024 + ks*32 + q*8)
                                             : (segB + (size_t)brow*1024 + (ks-32)*32 + q*8);
        ABu av; av.u4 = *(const uint4*)ap;
        ABu b0f, b1f;
        b0f.u4 = *(const uint4*)(Wp + ((size_t)(ks*2+0)*64 + L)*8);
        b1f.u4 = *(const uint4*)(Wp + ((size_t)(ks*2+1)*64 + L)*8);
        a0 = MFMA(av.v, b0f.v, a0);
        a1 = MFMA(av.v, b1f.v, a1);
      }
      for (int r=0;r<4;++r){
        int bb = w*16 + q*4 + r;
        s_gb[bb*32 + ccol]      = a0[r] + s_bias[ccol];
        s_gb[bb*32 + 16 + ccol] = a1[r] + s_bias[16+ccol];
      }
      __syncthreads();
      unsigned short* xout = A.xh1 + ((s+1)&1)*65536;  // h1_{s-1}
      for (int rep=0;rep<2;++rep){
        int cell = tid + rep*256;
        int du = cell>>6, bb = cell&63;
        float gi=s_gb[bb*32+du*4+0], gf=s_gb[bb*32+du*4+1];
        float gg=s_gb[bb*32+du*4+2], go=s_gb[bb*32+du*4+3];
        float cprev = s_cst[du*64+bb];
        float c2 = sigf(gf)*cprev + sigf(gi)*tanhf_fast(gg);
        float h2 = sigf(go)*tanhf_fast(c2);
        float cn = 0.1f*cprev + 0.9f*c2;
        float hp = s_hst[du*64+bb];
        float hn = 0.1f*hp + 0.9f*h2;
        s_cst[du*64+bb] = cn; s_hst[du*64+bb] = hn;
        xout[(size_t)bb*1024 + cp*8 + du] = f2b(hn);
      }
    }
    gbar(A.bar, (++ep)*NBLKS);
    // ================= PHASE B =================
    if (cu < 128 && s < SS) {
      const unsigned short* Wp = A.W0p + (size_t)cu*48*2*512;
      const unsigned short* segAC = A.acbf + (s&1)*16384;
      const unsigned short* segP  = A.P + (size_t)s*64*256;
      const unsigned short* segH  = A.xh0 + ((s+1)&1)*65536;
      floatx4 a0 = {0.f,0.f,0.f,0.f}, a1 = {0.f,0.f,0.f,0.f};
      int brow = w*16 + ccol;
      for (int ks=0; ks<48; ++ks){
        const unsigned short* ap;
        if (ks < 8)       ap = segAC + (size_t)brow*256  + ks*32 + q*8;
        else if (ks < 16) ap = segP  + (size_t)brow*256  + (ks-8)*32 + q*8;
        else              ap = segH  + (size_t)brow*1024 + (ks-16)*32 + q*8;
        ABu av; av.u4 = *(const uint4*)ap;
        ABu b0f, b1f;
        b0f.u4 = *(const uint4*)(Wp + ((size_t)(ks*2+0)*64 + L)*8);
        b1f.u4 = *(const uint4*)(Wp + ((size_t)(ks*2+1)*64 + L)*8);
        a0 = MFMA(av.v, b0f.v, a0);
        a1 = MFMA(av.v, b1f.v, a1);
      }
      for (int r=0;r<4;++r){
        int bb = w*16 + q*4 + r;
        s_gb[bb*32 + ccol]      = a0[r] + s_bias[ccol];
        s_gb[bb*32 + 16 + ccol] = a1[r] + s_bias[16+ccol];
      }
      __syncthreads();
      unsigned short* xout = A.xh0 + (s&1)*65536;   // h0_s
      for (int rep=0;rep<2;++rep){
        int cell = tid + rep*256;
        int du = cell>>6, bb = cell&63;
        float gi=s_gb[bb*32+du*4+0], gf=s_gb[bb*32+du*4+1];
        float gg=s_gb[bb*32+du*4+2], go=s_gb[bb*32+du*4+3];
        float cprev = s_cst[du*64+bb];
        float c2 = sigf(gf)*cprev + sigf(gi)*tanhf_fast(gg);
        float h2 = sigf(go)*tanhf_fast(c2);
        float cn = 0.1f*cprev + 0.9f*c2;
        float hp = s_hst[du*64+bb];
        float hn = 0.1f*hp + 0.9f*h2;
        s_cst[du*64+bb] = cn; s_hst[du*64+bb] = hn;
        xout[(size_t)bb*1024 + cu*8 + du] = f2b(hn);
      }
    }
    if (cu >= 128 && cu < 139 && s >= 1) {
      // output projection for step s-1: [h1|ac] @ Wout^T
      const int nt = cu - 128; const int s1 = s - 1;
      const unsigned short* segH  = A.xh1 + (s1&1)*65536;
      const unsigned short* segAC = A.acbf + (s1&1)*16384;
      floatx4 acc = {0.f,0.f,0.f,0.f};
      int brow = w*16 + ccol;
      for (int ks=0; ks<40; ++ks){
        const unsigned short* ap = (ks < 32) ? (segH + (size_t)brow*1024 + ks*32 + q*8)
                                             : (segAC + (size_t)brow*256 + (ks-32)*32 + q*8);
        ABu av; av.u4 = *(const uint4*)ap;
        ABu bf; bf.u4 = *(const uint4*)(A.Woutp + ((size_t)(nt*40+ks)*64 + L)*8);
        acc = MFMA(av.v, bf.v, acc);
      }
      int j = nt*16 + ccol;
      for (int r=0;r<4;++r){
        int b = w*16 + q*4 + r;
        float val = acc[r];
        if (j < 160){
          int rr = j/80, cc2 = j%80;
          A.dout[(size_t)b*80000 + (size_t)cc2*1000 + s1*2 + rr] = val;
        } else if (j < 162){
          A.dout[5120000 + (size_t)b*1000 + s1*2 + (j-160)] = val + A.probb[j-160];
        }
      }
    }
    gbar(A.bar, (++ep)*NBLKS);
  }
}

// ---------------- host launcher ----------------

extern "C" void kernel_launch(void* const* d_in, const int* in_sizes, int n_in,
                              void* d_out, int out_size, void* d_ws, size_t ws_size,
                              hipStream_t stream)
{
  const float* enc   = (const float*)d_in[0];
  const int*   tlen  = (const int*)d_in[1];
  const float* ftgt  = (const float*)d_in[2];
  const float* aew   = (const float*)d_in[3];
  const float* aeb   = (const float*)d_in[4];
  const float* adw   = (const float*)d_in[5];
  const float* aaw   = (const float*)d_in[6];
  const float* acw   = (const float*)d_in[7];
  const float* aww   = (const float*)d_in[8];
  const float* awb   = (const float*)d_in[9];
  const float* pw0   = (const float*)d_in[10];
  const float* pb0   = (const float*)d_in[11];
  const float* pw1   = (const float*)d_in[12];
  const float* pb1   = (const float*)d_in[13];
  const float* l0wih = (const float*)d_in[14];
  const float* l0whh = (const float*)d_in[15];
  const float* l0bih = (const float*)d_in[16];
  const float* l0bhh = (const float*)d_in[17];
  const float* l1wih = (const float*)d_in[18];
  const float* l1whh = (const float*)d_in[19];
  const float* l1bih = (const float*)d_in[20];
  const float* l1bhh = (const float*)d_in[21];
  const float* fow   = (const float*)d_in[22];
  const float* pow_  = (const float*)d_in[23];
  const float* pob   = (const float*)d_in[24];
  float* dout = (float*)d_out;

  char* ws = (char*)d_ws;
  size_t off = 0;
  auto alloc = [&](size_t bytes)->void*{
    void* p = (void*)(ws + off);
    off += (bytes + 255) & ~(size_t)255;
    return p;
  };

  unsigned short* pmb   = (unsigned short*)alloc((size_t)64*200*128*2);
  unsigned short* encb  = (unsigned short*)alloc((size_t)64*200*256*2);
  unsigned short* W2f   = (unsigned short*)alloc((size_t)8*64*8*2);
  unsigned short* Wdeck = (unsigned short*)alloc((size_t)1024*128*2);
  unsigned short* W0p   = (unsigned short*)alloc((size_t)128*48*2*512*2);
  unsigned short* W1p   = (unsigned short*)alloc((size_t)128*64*2*512*2);
  float* b0p            = (float*)alloc((size_t)4096*4);
  float* b1p            = (float*)alloc((size_t)4096*4);
  unsigned short* w0pp  = (unsigned short*)alloc((size_t)16*5*512*2);
  unsigned short* w1pp  = (unsigned short*)alloc((size_t)16*8*512*2);
  unsigned short* C1    = (unsigned short*)alloc((size_t)32000*256*2);
  unsigned short* P     = (unsigned short*)alloc((size_t)32000*256*2);
  unsigned short* Woutp = (unsigned short*)alloc((size_t)11*40*512*2);
  unsigned short* xh0   = (unsigned short*)alloc((size_t)2*65536*2);
  unsigned short* xh1   = (unsigned short*)alloc((size_t)2*65536*2);
  unsigned short* acbf  = (unsigned short*)alloc((size_t)2*16384*2);
  unsigned int* bar     = (unsigned int*)alloc(256);

  hipMemsetAsync(bar, 0, 256, stream);

  k_pm     <<<6400, 256, 0, stream>>>(enc, aew, aeb, pmb);
  k_encb   <<<12800,256, 0, stream>>>(enc, encb);
  k_w2f    <<<1,    256, 0, stream>>>(aaw, acw, W2f);
  k_wdeck  <<<512,  256, 0, stream>>>(adw, Wdeck);
  k_packlstm<<<1536,256, 0, stream>>>(l0wih, l0whh, W0p, 512, 48);
  k_packlstm<<<2048,256, 0, stream>>>(l1wih, l1whh, W1p, 1024, 64);
  k_bias   <<<16,   256, 0, stream>>>(l0bih, l0bhh, l1bih, l1bhh, b0p, b1p);
  k_packgen<<<20,   256, 0, stream>>>(pw0, w0pp, 256, 160);
  k_packgen<<<32,   256, 0, stream>>>(pw1, w1pp, 256, 256);
  k_woutp  <<<110,  256, 0, stream>>>(fow, pow_, Woutp);
  k_pre1   <<<2000, 256, 0, stream>>>(ftgt, w0pp, pb0, C1);
  k_pre2   <<<2000, 256, 0, stream>>>(C1, w1pp, pb1, P);

  PArgs A;
  A.tlen = tlen; A.ww = aww; A.wwb = awb; A.probb = pob;
  A.pmb = pmb; A.encb = encb; A.W2f = W2f; A.Wdeck = Wdeck;
  A.W0p = W0p; A.W1p = W1p; A.b0p = b0p; A.b1p = b1p;
  A.P = P; A.Woutp = Woutp;
  A.xh0 = xh0; A.xh1 = xh1; A.acbf = acbf;
  A.bar = bar; A.dout = dout;

  k_decoder<<<NBLKS, 256, 0, stream>>>(A);
}

// Round 2
// 71443.915 us; speedup vs baseline: 3.1332x; 3.1332x over previous
//
#include <hip/hip_runtime.h>

#define SS 500
#define NBLKS 256
#define NSLOT 64
#define DYN_LDS 149632

typedef __bf16 bf16_t;
typedef bf16_t bf16x8 __attribute__((ext_vector_type(8)));
typedef float floatx4 __attribute__((ext_vector_type(4)));

union ABu { uint4 u4; bf16x8 v; unsigned short us[8]; };

#define MFMA(a,b,c) __builtin_amdgcn_mfma_f32_16x16x32_bf16((a),(b),(c),0,0,0)

__device__ __forceinline__ float b2f(unsigned short u){
  union { unsigned int ui; float f; } x; x.ui = ((unsigned int)u) << 16; return x.f;
}
__device__ __forceinline__ unsigned short f2b(float f){
  union { float f; unsigned int ui; } x; x.f = f;
  unsigned int r = x.ui + 0x7FFFu + ((x.ui >> 16) & 1u);
  return (unsigned short)(r >> 16);
}
__device__ __forceinline__ float sigf(float x){ return 1.f/(1.f + __expf(-x)); }
__device__ __forceinline__ float tanhf_fast(float x){
  x = fminf(fmaxf(x, -15.f), 15.f);
  float e = __expf(2.f*x);
  return (e - 1.f)/(e + 1.f);
}

// ---- fast grid barrier: spread arrival counters + master broadcast flag ----
// slots: NSLOT counters, 128B apart (4 blocks each). Master (block NBLKS-1)
// wave0 polls all slots in parallel, then releases a single flag.
__device__ __forceinline__ void gbar(unsigned int* slots, unsigned int* flag,
                                     unsigned int ep, int is_master){
  __syncthreads();
  if (threadIdx.x == 0){
    __hip_atomic_fetch_add(&slots[(blockIdx.x & (NSLOT-1)) * 32], 1u,
                           __ATOMIC_RELEASE, __HIP_MEMORY_SCOPE_AGENT);
  }
  if (is_master){
    if (threadIdx.x < 64){
      for(;;){
        unsigned int v = __hip_atomic_load(&slots[threadIdx.x * 32],
                                           __ATOMIC_ACQUIRE, __HIP_MEMORY_SCOPE_AGENT);
        int t = (int)v;
        t += __shfl_xor(t, 1);  t += __shfl_xor(t, 2);  t += __shfl_xor(t, 4);
        t += __shfl_xor(t, 8);  t += __shfl_xor(t, 16); t += __shfl_xor(t, 32);
        if ((unsigned int)t >= ep * NBLKS) break;
        __builtin_amdgcn_s_sleep(1);
      }
      if (threadIdx.x == 0)
        __hip_atomic_store(flag, ep, __ATOMIC_RELEASE, __HIP_MEMORY_SCOPE_AGENT);
    }
  } else {
    if (threadIdx.x == 0){
      while (__hip_atomic_load(flag, __ATOMIC_ACQUIRE, __HIP_MEMORY_SCOPE_AGENT) < ep)
        __builtin_amdgcn_s_sleep(1);
    }
  }
  __syncthreads();
}

// ---------------- prep kernels ----------------

__global__ void k_pm(const float* __restrict__ enc, const float* __restrict__ ew,
                     const float* __restrict__ eb, unsigned short* __restrict__ pmb){
  int id = blockIdx.x*256 + threadIdx.x;
  if (id >= 64*200*128) return;
  int h = id & 127; int bt = id >> 7;
  const float* er = enc + (size_t)bt*256;
  const float* wr = ew + (size_t)h*256;
  float a0=eb[h], a1=0.f, a2=0.f, a3=0.f;
  for (int k=0;k<256;k+=4){
    a0 += er[k]*wr[k]; a1 += er[k+1]*wr[k+1]; a2 += er[k+2]*wr[k+2]; a3 += er[k+3]*wr[k+3];
  }
  pmb[id] = f2b((a0+a1)+(a2+a3));
}

__global__ void k_encb(const float* __restrict__ enc, unsigned short* __restrict__ encb){
  int id = blockIdx.x*256 + threadIdx.x;
  if (id >= 64*200*256) return;
  encb[id] = f2b(enc[id]);
}

__global__ void k_wdeck(const float* __restrict__ wd, unsigned short* __restrict__ dst){
  int id = blockIdx.x*256 + threadIdx.x;
  if (id >= 1024*128) return;
  int k = id >> 7, h = id & 127;
  dst[id] = f2b(wd[(size_t)h*1024 + k]);
}

__global__ void k_w2f(const float* __restrict__ attw, const float* __restrict__ convw,
                      unsigned short* __restrict__ w2f){
  __shared__ float s_w2[128*31];
  int tid = threadIdx.x;
  for (int i = tid; i < 128*31; i += 256){
    int h = i / 31, k = i % 31;
    float v = 0.f;
    for (int c=0;c<32;++c) v += attw[h*32+c]*convw[c*31+k];
    s_w2[i] = v;
  }
  __syncthreads();
  for (int i = tid; i < 512; i += 256){
    int nt = i >> 6, lane = i & 63;
    int h = nt*16 + (lane&15);
    for (int j=0;j<8;++j){
      int k = (lane>>4)*8 + j;
      w2f[(nt*64+lane)*8+j] = f2b(k < 31 ? s_w2[h*31+k] : 0.f);
    }
  }
}

__global__ void k_packlstm(const float* __restrict__ wih, const float* __restrict__ whh,
                           unsigned short* __restrict__ dst, int Kih, int NKS){
  int id = blockIdx.x*256 + threadIdx.x;
  if (id >= 128*NKS*64) return;
  int lane = id & 63; int t = id >> 6; int cu = t / NKS;
  for (int nt=0; nt<2; ++nt){
    int n = nt*16 + (lane&15);
    int du = n>>2, g = n&3;
    int row = g*1024 + cu*8 + du;
    for (int j=0;j<8;++j){
      int k = (t % NKS)*32 + ((lane>>4)*8) + j;
      float v = (k < Kih) ? wih[(size_t)row*Kih + k] : whh[(size_t)row*1024 + (k - Kih)];
      dst[((size_t)(t*2+nt)*64 + lane)*8 + j] = f2b(v);
    }
  }
}

__global__ void k_bias(const float* bi0,const float* bh0,const float* bi1,const float* bh1,
                       float* b0p, float* b1p){
  int id = blockIdx.x*256 + threadIdx.x;
  if (id >= 4096) return;
  int cu = id>>5, n = id&31, du = n>>2, g = n&3;
  int row = g*1024 + cu*8 + du;
  b0p[id] = bi0[row] + bh0[row];
  b1p[id] = bi1[row] + bh1[row];
}

__global__ void k_packgen(const float* __restrict__ src, unsigned short* __restrict__ dst,
                          int N, int K){
  int tot = (N/16)*(K/32)*64;
  int id = blockIdx.x*256 + threadIdx.x;
  if (id >= tot) return;
  int lane = id & 63; int t = id >> 6;
  int nks = K/32;
  int n = (t / nks)*16 + (lane&15);
  for (int j=0;j<8;++j){
    int k = (t % nks)*32 + (lane>>4)*8 + j;
    dst[((size_t)t*64 + lane)*8 + j] = f2b(src[(size_t)n*K + k]);
  }
}

__global__ void k_woutp(const float* __restrict__ fw, const float* __restrict__ pw,
                        unsigned short* __restrict__ dst){
  int id = blockIdx.x*256 + threadIdx.x;
  if (id >= 11*40*64) return;
  int lane = id & 63; int t = id >> 6;
  int n = (t/40)*16 + (lane&15);
  for (int j=0;j<8;++j){
    int k = (t%40)*32 + (lane>>4)*8 + j;
    float v = 0.f;
    if (n < 160) v = fw[(size_t)n*1280 + k];
    else if (n < 162) v = pw[(size_t)(n-160)*1280 + k];
    dst[((size_t)t*64 + lane)*8 + j] = f2b(v);
  }
}

__global__ void k_pre1(const float* __restrict__ ftgt, const unsigned short* __restrict__ w0p,
                       const float* __restrict__ b0, unsigned short* __restrict__ C1){
  int mt = blockIdx.x;
  int tid = threadIdx.x, w = tid>>6, L = tid&63, ccol = L&15, q = L>>4;
  int sb0 = mt*16; int s = sb0 >> 6; int b0r = sb0 & 63;
  floatx4 z = {0.f,0.f,0.f,0.f};
  floatx4 acc[4] = {z,z,z,z};
  for (int ks=0; ks<5; ++ks){
    ABu av;
    if (s == 0){ av.u4.x=0; av.u4.y=0; av.u4.z=0; av.u4.w=0; }
    else {
      int b = b0r + ccol;
      for (int j=0;j<8;++j){
        int jj = ks*32 + q*8 + j;
        av.us[j] = f2b(ftgt[(size_t)b*80000 + (size_t)(jj%80)*1000 + (size_t)(s-1)*2 + (jj/80)]);
      }
    }
    for (int i=0;i<4;++i){
      ABu bf; bf.u4 = *(const uint4*)(w0p + ((size_t)((w*4+i)*5 + ks)*64 + L)*8);
      acc[i] = MFMA(av.v, bf.v, acc[i]);
    }
  }
  for (int i=0;i<4;++i){
    int icol = (w*4+i)*16 + ccol;
    float bia = b0[icol];
    for (int r=0;r<4;++r){
      int sb = sb0 + q*4 + r;
      C1[(size_t)sb*256 + icol] = f2b(fmaxf(acc[i][r] + bia, 0.f));
    }
  }
}

__global__ void k_pre2(const unsigned short* __restrict__ C1, const unsigned short* __restrict__ w1p,
                       const float* __restrict__ b1, unsigned short* __restrict__ P){
  int mt = blockIdx.x;
  int tid = threadIdx.x, w = tid>>6, L = tid&63, ccol = L&15, q = L>>4;
  int sb0 = mt*16;
  floatx4 z = {0.f,0.f,0.f,0.f};
  floatx4 acc[4] = {z,z,z,z};
  for (int ks=0; ks<8; ++ks){
    ABu av; av.u4 = *(const uint4*)(C1 + (size_t)(sb0+ccol)*256 + ks*32 + q*8);
    for (int i=0;i<4;++i){
      ABu bf; bf.u4 = *(const uint4*)(w1p + ((size_t)((w*4+i)*8 + ks)*64 + L)*8);
      acc[i] = MFMA(av.v, bf.v, acc[i]);
    }
  }
  for (int i=0;i<4;++i){
    int icol = (w*4+i)*16 + ccol;
    float bia = b1[icol];
    for (int r=0;r<4;++r){
      int sb = sb0 + q*4 + r;
      P[(size_t)sb*256 + icol] = f2b(fmaxf(acc[i][r] + bia, 0.f));
    }
  }
}

// ---------------- persistent decoder ----------------

struct PArgs {
  const int* tlen;
  const float* ww; const float* wwb; const float* probb;
  const unsigned short* pmb; const unsigned short* encb;
  const unsigned short* W2f; const unsigned short* Wdeck;
  const unsigned short* W0p; const unsigned short* W1p;
  const float* b0p; const float* b1p;
  const unsigned short* P; const unsigned short* Woutp;
  unsigned short* xh0; unsigned short* xh1; unsigned short* acbf;
  unsigned int* bar; unsigned int* flag;
  float* dout;
};

__global__ __launch_bounds__(256, 1) void k_decoder(PArgs A)
{
  const int cu = blockIdx.x;
  const int tid = threadIdx.x;
  const int w = tid>>6, L = tid&63;
  const int ccol = L&15, q = L>>4;
  const int is_master = (cu == NBLKS-1);

  extern __shared__ char pool[];
  // role-based LDS layout
  unsigned short* sW;     // LSTM weight fragments (LDS-resident all steps)
  unsigned short* sWOUT = nullptr;
  float* sGB; float* sCST; float* sBIAS;
  if (cu < 128){
    sW    = (unsigned short*)pool;                 // 98304 B (48*2*512 us)
    sWOUT = (unsigned short*)(pool + 98304);       // 40960 B (only cu 64..74)
    sGB   = (float*)(pool + 139264);               // 8192 B
    sCST  = (float*)(pool + 147456);               // 2048 B
    sBIAS = (float*)(pool + 149504);               // 128 B
  } else {
    sW    = (unsigned short*)pool;                 // 131072 B (64*2*512 us)
    sGB   = (float*)(pool + 131072);
    sCST  = (float*)(pool + 139264);
    sBIAS = (float*)(pool + 141312);
  }

  __shared__ unsigned short s_ahi[240], s_alo[240];
  __shared__ float s_e[256];
  __shared__ float s_red[256];
  __shared__ float s_dp[128];
  __shared__ float s_ww[128];

  // ---- init: stage weights into LDS, zero state ----
  if (cu < 128){
    const unsigned short* src = A.W0p + (size_t)cu*48*2*512;
    for (int i = tid*8; i < 48*2*512; i += 2048)
      *(uint4*)(sW + i) = *(const uint4*)(src + i);
    if (cu >= 64 && cu < 75){
      const unsigned short* s2 = A.Woutp + (size_t)(cu-64)*40*512;
      for (int i = tid*8; i < 40*512; i += 2048)
        *(uint4*)(sWOUT + i) = *(const uint4*)(s2 + i);
    }
    if (tid < 32) sBIAS[tid] = A.b0p[cu*32 + tid];
  } else {
    const unsigned short* src = A.W1p + (size_t)(cu-128)*64*2*512;
    for (int i = tid*8; i < 64*2*512; i += 2048)
      *(uint4*)(sW + i) = *(const uint4*)(src + i);
    if (tid < 32) sBIAS[tid] = A.b1p[(cu-128)*32 + tid];
  }
  for (int i = tid; i < 512; i += 256) sCST[i] = 0.f;

  float accv = 0.f; int lenb = 0; float wwbv = 0.f;
  if (cu < 64) {
    lenb = A.tlen[cu];
    wwbv = A.wwb[0];
    float inv = 1.f / (float)lenb;
    for (int i = tid; i < 240; i += 256) {
      int t = i - 15;
      float v = (t >= 0 && t < 200 && t < lenb) ? inv : 0.f;
      unsigned short hi = f2b(v);
      s_ahi[i] = hi; s_alo[i] = f2b(v - b2f(hi));
    }
    if (tid < 200) accv = (tid < lenb) ? inv : 0.f;
    if (tid < 128) s_ww[tid] = A.ww[tid];
  }
  // zero h-state ring buffers (xh0: 2 slots, xh1: 4 slots)
  for (int i = tid; i < 512;  i += 256) A.xh0[cu*512  + i] = 0;
  for (int i = tid; i < 1024; i += 256) A.xh1[cu*1024 + i] = 0;

  unsigned int ep = 0;
  gbar(A.bar, A.flag, ++ep, is_master);

  for (int s = 0; s <= SS+1; ++s) {
    // ================= PHASE A =================
    if (cu < 64 && s < SS) {
      const int b = cu;
      const unsigned short* xh0r = A.xh0 + ((s+1)&1)*65536;
      // ---- dp[h] = h0_{s-1} @ Wdec^T ----
      {
        int h = tid & 127, half = tid >> 7;
        const unsigned short* h0r = xh0r + b*1024 + half*512;
        const unsigned short* wd = A.Wdeck + (size_t)half*512*128 + h;
        float a0=0.f,a1=0.f,a2=0.f,a3=0.f;
        for (int k=0;k<512;k+=4){
          a0 += b2f(h0r[k  ])*b2f(wd[(size_t)(k  )*128]);
          a1 += b2f(h0r[k+1])*b2f(wd[(size_t)(k+1)*128]);
          a2 += b2f(h0r[k+2])*b2f(wd[(size_t)(k+2)*128]);
          a3 += b2f(h0r[k+3])*b2f(wd[(size_t)(k+3)*128]);
        }
        s_red[tid] = (a0+a1)+(a2+a3);
        __syncthreads();
        if (tid < 128) s_dp[tid] = s_red[tid] + s_red[tid+128];
        __syncthreads();
      }
      // ---- conv (MFMA, hi/lo split) + scores ----
      {
        ABu w2f[8];
        for (int nt=0; nt<8; ++nt) w2f[nt].u4 = *(const uint4*)(A.W2f + (nt*64 + L)*8);
        const unsigned short* pmrow = A.pmb + (size_t)b*200*128;
        for (int mt = w; mt < 13; mt += 4) {
          ABu ahi, alo;
          int abase = mt*16 + ccol + q*8;
          for (int j=0;j<8;++j){ ahi.us[j] = s_ahi[abase+j]; alo.us[j] = s_alo[abase+j]; }
          floatx4 acc[8];
          for (int nt=0;nt<8;++nt){
            floatx4 zz = {0.f,0.f,0.f,0.f};
            zz = MFMA(ahi.v, w2f[nt].v, zz);
            zz = MFMA(alo.v, w2f[nt].v, zz);
            acc[nt] = zz;
          }
          for (int r=0;r<4;++r){
            int t = mt*16 + q*4 + r;
            float part = 0.f;
            if (t < 200) {
              for (int nt=0;nt<8;++nt){
                int h = nt*16 + ccol;
                float v = acc[nt][r] + b2f(pmrow[t*128+h]) + s_dp[h];
                part += s_ww[h] * tanhf_fast(v);
              }
            }
            part += __shfl_xor(part, 1);
            part += __shfl_xor(part, 2);
            part += __shfl_xor(part, 4);
            part += __shfl_xor(part, 8);
            if (t < 200 && ccol == 0)
              s_e[t] = (t < lenb) ? (part + wwbv) : -1e30f;
          }
        }
      }
      __syncthreads();
      // ---- softmax + cumulative attention update ----
      {
        float v = (tid < 200) ? s_e[tid] : -1e30f;
        s_red[tid] = v; __syncthreads();
        for (int off=128; off>0; off>>=1){
          if (tid < off) s_red[tid] = fmaxf(s_red[tid], s_red[tid+off]);
          __syncthreads();
        }
        float m = s_red[0]; __syncthreads();
        float ex = (tid < 200) ? __expf(v - m) : 0.f;
        s_red[tid] = ex; __syncthreads();
        for (int off=128; off>0; off>>=1){
          if (tid < off) s_red[tid] += s_red[tid+off];
          __syncthreads();
        }
        float inv = 1.f / s_red[0];
        if (tid < 200){
          float aw = ex * inv;
          s_e[tid] = aw;
          A.dout[5184000 + (size_t)b*100000 + (size_t)s*200 + tid] = aw;
          accv = (s == 0) ? aw : (accv + aw);
          unsigned short hi = f2b(accv);
          s_ahi[15+tid] = hi; s_alo[15+tid] = f2b(accv - b2f(hi));
        }
      }
      __syncthreads();
      // ---- ac[c] = sum_t aw[t]*enc[b,t,c] ----
      {
        const unsigned short* er = A.encb + (size_t)b*200*256 + tid;
        float a0=0.f,a1=0.f,a2=0.f,a3=0.f;
        for (int t=0;t<200;t+=4){
          a0 += s_e[t  ]*b2f(er[(size_t)(t  )*256]);
          a1 += s_e[t+1]*b2f(er[(size_t)(t+1)*256]);
          a2 += s_e[t+2]*b2f(er[(size_t)(t+2)*256]);
          a3 += s_e[t+3]*b2f(er[(size_t)(t+3)*256]);
        }
        A.acbf[(s&3)*16384 + b*256 + tid] = f2b((a0+a1)+(a2+a3));
      }
    }
    if (cu >= 64 && cu < 75 && s >= 2) {
      // ---- output projection for step s-2: [h1|ac] @ Wout^T ----
      const int nt = cu - 64; const int s2 = s - 2;
      const unsigned short* segH  = A.xh1 + (size_t)(s2&3)*65536;
      const unsigned short* segAC = A.acbf + (s2&3)*16384;
      floatx4 acc = {0.f,0.f,0.f,0.f};
      int brow = w*16 + ccol;
      for (int ks=0; ks<40; ++ks){
        const unsigned short* ap = (ks < 32) ? (segH + (size_t)brow*1024 + ks*32 + q*8)
                                             : (segAC + (size_t)brow*256 + (ks-32)*32 + q*8);
        ABu av; av.u4 = *(const uint4*)ap;
        ABu bf; bf.u4 = *(const uint4*)(sWOUT + ((size_t)ks*64 + L)*8);
        acc = MFMA(av.v, bf.v, acc);
      }
      int j = nt*16 + ccol;
      for (int r=0;r<4;++r){
        int b = w*16 + q*4 + r;
        float val = acc[r];
        if (j < 160){
          int rr = j/80, cc2 = j%80;
          A.dout[(size_t)b*80000 + (size_t)cc2*1000 + s2*2 + rr] = val;
        } else if (j < 162){
          A.dout[5120000 + (size_t)b*1000 + s2*2 + (j-160)] = val + A.probb[j-160];
        }
      }
    }
    if (cu >= 128 && s >= 1 && s <= SS) {
      // ---- LSTM1 for step s-1 ----
      const int cp = cu - 128;
      const unsigned short* segA = A.xh0 + ((s+1)&1)*65536;          // h0_{s-1}
      const unsigned short* segB = A.xh1 + (size_t)((s-2)&3)*65536;  // h1_{s-2}
      floatx4 a0 = {0.f,0.f,0.f,0.f}, a1 = {0.f,0.f,0.f,0.f};
      int brow = w*16 + ccol;
      for (int ks=0; ks<64; ++ks){
        const unsigned short* ap = (ks < 32) ? (segA + (size_t)brow*1024 + ks*32 + q*8)
                                             : (segB + (size_t)brow*1024 + (ks-32)*32 + q*8);
        ABu av; av.u4 = *(const uint4*)ap;
        ABu b0f, b1f;
        b0f.u4 = *(const uint4*)(sW + ((size_t)(ks*2+0)*64 + L)*8);
        b1f.u4 = *(const uint4*)(sW + ((size_t)(ks*2+1)*64 + L)*8);
        a0 = MFMA(av.v, b0f.v, a0);
        a1 = MFMA(av.v, b1f.v, a1);
      }
      for (int r=0;r<4;++r){
        int bb = w*16 + q*4 + r;
        sGB[bb*32 + ccol]      = a0[r] + sBIAS[ccol];
        sGB[bb*32 + 16 + ccol] = a1[r] + sBIAS[16+ccol];
      }
      __syncthreads();
      unsigned short* xout = A.xh1 + (size_t)((s-1)&3)*65536;        // h1_{s-1}
      const unsigned short* hprev = segB;
      for (int rep=0;rep<2;++rep){
        int cell = tid + rep*256;
        int du = cell>>6, bb = cell&63;
        float gi=sGB[bb*32+du*4+0], gf=sGB[bb*32+du*4+1];
        float gg=sGB[bb*32+du*4+2], go=sGB[bb*32+du*4+3];
        float cprev = sCST[du*64+bb];
        float c2 = sigf(gf)*cprev + sigf(gi)*tanhf_fast(gg);
        float h2 = sigf(go)*tanhf_fast(c2);
        float cn = 0.1f*cprev + 0.9f*c2;
        float hp = b2f(hprev[(size_t)bb*1024 + cp*8 + du]);
        float hn = 0.1f*hp + 0.9f*h2;
        sCST[du*64+bb] = cn;
        xout[(size_t)bb*1024 + cp*8 + du] = f2b(hn);
      }
    }
    gbar(A.bar, A.flag, ++ep, is_master);
    // ================= PHASE B =================
    if (cu < 128 && s < SS) {
      // ---- LSTM0 for step s ----
      const unsigned short* segAC = A.acbf + (s&3)*16384;
      const unsigned short* segP  = A.P + (size_t)s*64*256;
      const unsigned short* segH  = A.xh0 + ((s+1)&1)*65536;         // h0_{s-1}
      floatx4 a0 = {0.f,0.f,0.f,0.f}, a1 = {0.f,0.f,0.f,0.f};
      int brow = w*16 + ccol;
      for (int ks=0; ks<48; ++ks){
        const unsigned short* ap;
        if (ks < 8)       ap = segAC + (size_t)brow*256  + ks*32 + q*8;
        else if (ks < 16) ap = segP  + (size_t)brow*256  + (ks-8)*32 + q*8;
        else              ap = segH  + (size_t)brow*1024 + (ks-16)*32 + q*8;
        ABu av; av.u4 = *(const uint4*)ap;
        ABu b0f, b1f;
        b0f.u4 = *(const uint4*)(sW + ((size_t)(ks*2+0)*64 + L)*8);
        b1f.u4 = *(const uint4*)(sW + ((size_t)(ks*2+1)*64 + L)*8);
        a0 = MFMA(av.v, b0f.v, a0);
        a1 = MFMA(av.v, b1f.v, a1);
      }
      for (int r=0;r<4;++r){
        int bb = w*16 + q*4 + r;
        sGB[bb*32 + ccol]      = a0[r] + sBIAS[ccol];
        sGB[bb*32 + 16 + ccol] = a1[r] + sBIAS[16+ccol];
      }
      __syncthreads();
      unsigned short* xout = A.xh0 + (s&1)*65536;                    // h0_s
      const unsigned short* hprev = segH;
      for (int rep=0;rep<2;++rep){
        int cell = tid + rep*256;
        int du = cell>>6, bb = cell&63;
        float gi=sGB[bb*32+du*4+0], gf=sGB[bb*32+du*4+1];
        float gg=sGB[bb*32+du*4+2], go=sGB[bb*32+du*4+3];
        float cprev = sCST[du*64+bb];
        float c2 = sigf(gf)*cprev + sigf(gi)*tanhf_fast(gg);
        float h2 = sigf(go)*tanhf_fast(c2);
        float cn = 0.1f*cprev + 0.9f*c2;
        float hp = b2f(hprev[(size_t)bb*1024 + cu*8 + du]);
        float hn = 0.1f*hp + 0.9f*h2;
        sCST[du*64+bb] = cn;
        xout[(size_t)bb*1024 + cu*8 + du] = f2b(hn);
      }
    }
    gbar(A.bar, A.flag, ++ep, is_master);
  }
}

// ---------------- host launcher ----------------

extern "C" void kernel_launch(void* const* d_in, const int* in_sizes, int n_in,
                              void* d_out, int out_size, void* d_ws, size_t ws_size,
                              hipStream_t stream)
{
  const float* enc   = (const float*)d_in[0];
  const int*   tlen  = (const int*)d_in[1];
  const float* ftgt  = (const float*)d_in[2];
  const float* aew   = (const float*)d_in[3];
  const float* aeb   = (const float*)d_in[4];
  const float* adw   = (const float*)d_in[5];
  const float* aaw   = (const float*)d_in[6];
  const float* acw   = (const float*)d_in[7];
  const float* aww   = (const float*)d_in[8];
  const float* awb   = (const float*)d_in[9];
  const float* pw0   = (const float*)d_in[10];
  const float* pb0   = (const float*)d_in[11];
  const float* pw1   = (const float*)d_in[12];
  const float* pb1   = (const float*)d_in[13];
  const float* l0wih = (const float*)d_in[14];
  const float* l0whh = (const float*)d_in[15];
  const float* l0bih = (const float*)d_in[16];
  const float* l0bhh = (const float*)d_in[17];
  const float* l1wih = (const float*)d_in[18];
  const float* l1whh = (const float*)d_in[19];
  const float* l1bih = (const float*)d_in[20];
  const float* l1bhh = (const float*)d_in[21];
  const float* fow   = (const float*)d_in[22];
  const float* pow_  = (const float*)d_in[23];
  const float* pob   = (const float*)d_in[24];
  float* dout = (float*)d_out;

  char* ws = (char*)d_ws;
  size_t off = 0;
  auto alloc = [&](size_t bytes)->void*{
    void* p = (void*)(ws + off);
    off += (bytes + 255) & ~(size_t)255;
    return p;
  };

  unsigned short* pmb   = (unsigned short*)alloc((size_t)64*200*128*2);
  unsigned short* encb  = (unsigned short*)alloc((size_t)64*200*256*2);
  unsigned short* W2f   = (unsigned short*)alloc((size_t)8*64*8*2);
  unsigned short* Wdeck = (unsigned short*)alloc((size_t)1024*128*2);
  unsigned short* W0p   = (unsigned short*)alloc((size_t)128*48*2*512*2);
  unsigned short* W1p   = (unsigned short*)alloc((size_t)128*64*2*512*2);
  float* b0p            = (float*)alloc((size_t)4096*4);
  float* b1p            = (float*)alloc((size_t)4096*4);
  unsigned short* w0pp  = (unsigned short*)alloc((size_t)16*5*512*2);
  unsigned short* w1pp  = (unsigned short*)alloc((size_t)16*8*512*2);
  unsigned short* C1    = (unsigned short*)alloc((size_t)32000*256*2);
  unsigned short* P     = (unsigned short*)alloc((size_t)32000*256*2);
  unsigned short* Woutp = (unsigned short*)alloc((size_t)11*40*512*2);
  unsigned short* xh0   = (unsigned short*)alloc((size_t)2*65536*2);
  unsigned short* xh1   = (unsigned short*)alloc((size_t)4*65536*2);
  unsigned short* acbf  = (unsigned short*)alloc((size_t)4*16384*2);
  unsigned int* bar     = (unsigned int*)alloc((size_t)NSLOT*128);
  unsigned int* flag    = (unsigned int*)alloc(256);

  hipMemsetAsync(bar, 0, (size_t)NSLOT*128, stream);
  hipMemsetAsync(flag, 0, 256, stream);

  k_pm     <<<6400, 256, 0, stream>>>(enc, aew, aeb, pmb);
  k_encb   <<<12800,256, 0, stream>>>(enc, encb);
  k_w2f    <<<1,    256, 0, stream>>>(aaw, acw, W2f);
  k_wdeck  <<<512,  256, 0, stream>>>(adw, Wdeck);
  k_packlstm<<<1536,256, 0, stream>>>(l0wih, l0whh, W0p, 512, 48);
  k_packlstm<<<2048,256, 0, stream>>>(l1wih, l1whh, W1p, 1024, 64);
  k_bias   <<<16,   256, 0, stream>>>(l0bih, l0bhh, l1bih, l1bhh, b0p, b1p);
  k_packgen<<<20,   256, 0, stream>>>(pw0, w0pp, 256, 160);
  k_packgen<<<32,   256, 0, stream>>>(pw1, w1pp, 256, 256);
  k_woutp  <<<110,  256, 0, stream>>>(fow, pow_, Woutp);
  k_pre1   <<<2000, 256, 0, stream>>>(ftgt, w0pp, pb0, C1);
  k_pre2   <<<2000, 256, 0, stream>>>(C1, w1pp, pb1, P);

  PArgs A;
  A.tlen = tlen; A.ww = aww; A.wwb = awb; A.probb = pob;
  A.pmb = pmb; A.encb = encb; A.W2f = W2f; A.Wdeck = Wdeck;
  A.W0p = W0p; A.W1p = W1p; A.b0p = b0p; A.b1p = b1p;
  A.P = P; A.Woutp = Woutp;
  A.xh0 = xh0; A.xh1 = xh1; A.acbf = acbf;
  A.bar = bar; A.flag = flag; A.dout = dout;

  hipFuncSetAttribute((const void*)k_decoder,
                      hipFuncAttributeMaxDynamicSharedMemorySize, DYN_LDS);
  k_decoder<<<NBLKS, 256, DYN_LDS, stream>>>(A);
}

// Round 3
// 26390.271 us; speedup vs baseline: 8.4823x; 2.7072x over previous
//
#include <hip/hip_runtime.h>

#define SS 500
#define NBLKS 256
#define NSLOT 64
#define DYN_LDS 149632

typedef __bf16 bf16_t;
typedef bf16_t bf16x8 __attribute__((ext_vector_type(8)));
typedef float floatx4 __attribute__((ext_vector_type(4)));

union ABu { uint4 u4; bf16x8 v; unsigned short us[8]; };

#define MFMA(a,b,c) __builtin_amdgcn_mfma_f32_16x16x32_bf16((a),(b),(c),0,0,0)

__device__ __forceinline__ float b2f(unsigned short u){
  union { unsigned int ui; float f; } x; x.ui = ((unsigned int)u) << 16; return x.f;
}
__device__ __forceinline__ unsigned short f2b(float f){
  union { float f; unsigned int ui; } x; x.f = f;
  unsigned int r = x.ui + 0x7FFFu + ((x.ui >> 16) & 1u);
  return (unsigned short)(r >> 16);
}
__device__ __forceinline__ float sigf(float x){ return 1.f/(1.f + __expf(-x)); }
__device__ __forceinline__ float tanhf_fast(float x){
  x = fminf(fmaxf(x, -15.f), 15.f);
  float e = __expf(2.f*x);
  return (e - 1.f)/(e + 1.f);
}

// ---- grid barrier v3: relaxed spins, fences hoisted to once per barrier ----
__device__ __forceinline__ void gbar(unsigned int* slots, unsigned int* flag,
                                     unsigned int ep, int is_master){
  __syncthreads();
  if (threadIdx.x == 0){
    __builtin_amdgcn_fence(__ATOMIC_RELEASE, "agent");   // one wbl2 per block
    __hip_atomic_fetch_add(&slots[(blockIdx.x & (NSLOT-1)) * 32], 1u,
                           __ATOMIC_RELAXED, __HIP_MEMORY_SCOPE_AGENT);
  }
  if (is_master){
    if (threadIdx.x < 64){
      for(;;){
        unsigned int v = __hip_atomic_load(&slots[threadIdx.x * 32],
                                           __ATOMIC_RELAXED, __HIP_MEMORY_SCOPE_AGENT);
        int t = (int)v;
        t += __shfl_xor(t, 1);  t += __shfl_xor(t, 2);  t += __shfl_xor(t, 4);
        t += __shfl_xor(t, 8);  t += __shfl_xor(t, 16); t += __shfl_xor(t, 32);
        if ((unsigned int)t >= ep * NBLKS) break;
        __builtin_amdgcn_s_sleep(2);
      }
      __builtin_amdgcn_fence(__ATOMIC_ACQUIRE, "agent"); // one inv for master
      if (threadIdx.x == 0)
        __hip_atomic_store(flag, ep, __ATOMIC_RELAXED, __HIP_MEMORY_SCOPE_AGENT);
    }
  } else {
    if (threadIdx.x == 0){
      while (__hip_atomic_load(flag, __ATOMIC_RELAXED, __HIP_MEMORY_SCOPE_AGENT) < ep)
        __builtin_amdgcn_s_sleep(2);
      __builtin_amdgcn_fence(__ATOMIC_ACQUIRE, "agent"); // one inv per block
    }
  }
  __syncthreads();
}

// ---------------- prep kernels ----------------

__global__ void k_pm(const float* __restrict__ enc, const float* __restrict__ ew,
                     const float* __restrict__ eb, unsigned short* __restrict__ pmb){
  int id = blockIdx.x*256 + threadIdx.x;
  if (id >= 64*200*128) return;
  int h = id & 127; int bt = id >> 7;
  const float* er = enc + (size_t)bt*256;
  const float* wr = ew + (size_t)h*256;
  float a0=eb[h], a1=0.f, a2=0.f, a3=0.f;
  for (int k=0;k<256;k+=4){
    a0 += er[k]*wr[k]; a1 += er[k+1]*wr[k+1]; a2 += er[k+2]*wr[k+2]; a3 += er[k+3]*wr[k+3];
  }
  pmb[id] = f2b((a0+a1)+(a2+a3));
}

__global__ void k_encb(const float* __restrict__ enc, unsigned short* __restrict__ encb){
  int id = blockIdx.x*256 + threadIdx.x;
  if (id >= 64*200*256) return;
  encb[id] = f2b(enc[id]);
}

__global__ void k_w2f(const float* __restrict__ attw, const float* __restrict__ convw,
                      unsigned short* __restrict__ w2f){
  __shared__ float s_w2[128*31];
  int tid = threadIdx.x;
  for (int i = tid; i < 128*31; i += 256){
    int h = i / 31, k = i % 31;
    float v = 0.f;
    for (int c=0;c<32;++c) v += attw[h*32+c]*convw[c*31+k];
    s_w2[i] = v;
  }
  __syncthreads();
  for (int i = tid; i < 512; i += 256){
    int nt = i >> 6, lane = i & 63;
    int h = nt*16 + (lane&15);
    for (int j=0;j<8;++j){
      int k = (lane>>4)*8 + j;
      w2f[(nt*64+lane)*8+j] = f2b(k < 31 ? s_w2[h*31+k] : 0.f);
    }
  }
}

__global__ void k_packlstm(const float* __restrict__ wih, const float* __restrict__ whh,
                           unsigned short* __restrict__ dst, int Kih, int NKS){
  int id = blockIdx.x*256 + threadIdx.x;
  if (id >= 128*NKS*64) return;
  int lane = id & 63; int t = id >> 6; int cu = t / NKS;
  for (int nt=0; nt<2; ++nt){
    int n = nt*16 + (lane&15);
    int du = n>>2, g = n&3;
    int row = g*1024 + cu*8 + du;
    for (int j=0;j<8;++j){
      int k = (t % NKS)*32 + ((lane>>4)*8) + j;
      float v = (k < Kih) ? wih[(size_t)row*Kih + k] : whh[(size_t)row*1024 + (k - Kih)];
      dst[((size_t)(t*2+nt)*64 + lane)*8 + j] = f2b(v);
    }
  }
}

__global__ void k_bias(const float* bi0,const float* bh0,const float* bi1,const float* bh1,
                       float* b0p, float* b1p){
  int id = blockIdx.x*256 + threadIdx.x;
  if (id >= 4096) return;
  int cu = id>>5, n = id&31, du = n>>2, g = n&3;
  int row = g*1024 + cu*8 + du;
  b0p[id] = bi0[row] + bh0[row];
  b1p[id] = bi1[row] + bh1[row];
}

__global__ void k_packgen(const float* __restrict__ src, unsigned short* __restrict__ dst,
                          int N, int K){
  int tot = (N/16)*(K/32)*64;
  int id = blockIdx.x*256 + threadIdx.x;
  if (id >= tot) return;
  int lane = id & 63; int t = id >> 6;
  int nks = K/32;
  int n = (t / nks)*16 + (lane&15);
  for (int j=0;j<8;++j){
    int k = (t % nks)*32 + (lane>>4)*8 + j;
    dst[((size_t)t*64 + lane)*8 + j] = f2b(src[(size_t)n*K + k]);
  }
}

__global__ void k_woutp(const float* __restrict__ fw, const float* __restrict__ pw,
                        unsigned short* __restrict__ dst){
  int id = blockIdx.x*256 + threadIdx.x;
  if (id >= 11*40*64) return;
  int lane = id & 63; int t = id >> 6;
  int n = (t/40)*16 + (lane&15);
  for (int j=0;j<8;++j){
    int k = (t%40)*32 + (lane>>4)*8 + j;
    float v = 0.f;
    if (n < 160) v = fw[(size_t)n*1280 + k];
    else if (n < 162) v = pw[(size_t)(n-160)*1280 + k];
    dst[((size_t)t*64 + lane)*8 + j] = f2b(v);
  }
}

__global__ void k_pre1(const float* __restrict__ ftgt, const unsigned short* __restrict__ w0p,
                       const float* __restrict__ b0, unsigned short* __restrict__ C1){
  int mt = blockIdx.x;
  int tid = threadIdx.x, w = tid>>6, L = tid&63, ccol = L&15, q = L>>4;
  int sb0 = mt*16; int s = sb0 >> 6; int b0r = sb0 & 63;
  floatx4 z = {0.f,0.f,0.f,0.f};
  floatx4 acc[4] = {z,z,z,z};
  for (int ks=0; ks<5; ++ks){
    ABu av;
    if (s == 0){ av.u4.x=0; av.u4.y=0; av.u4.z=0; av.u4.w=0; }
    else {
      int b = b0r + ccol;
      for (int j=0;j<8;++j){
        int jj = ks*32 + q*8 + j;
        av.us[j] = f2b(ftgt[(size_t)b*80000 + (size_t)(jj%80)*1000 + (size_t)(s-1)*2 + (jj/80)]);
      }
    }
    for (int i=0;i<4;++i){
      ABu bf; bf.u4 = *(const uint4*)(w0p + ((size_t)((w*4+i)*5 + ks)*64 + L)*8);
      acc[i] = MFMA(av.v, bf.v, acc[i]);
    }
  }
  for (int i=0;i<4;++i){
    int icol = (w*4+i)*16 + ccol;
    float bia = b0[icol];
    for (int r=0;r<4;++r){
      int sb = sb0 + q*4 + r;
      C1[(size_t)sb*256 + icol] = f2b(fmaxf(acc[i][r] + bia, 0.f));
    }
  }
}

__global__ void k_pre2(const unsigned short* __restrict__ C1, const unsigned short* __restrict__ w1p,
                       const float* __restrict__ b1, unsigned short* __restrict__ P){
  int mt = blockIdx.x;
  int tid = threadIdx.x, w = tid>>6, L = tid&63, ccol = L&15, q = L>>4;
  int sb0 = mt*16;
  floatx4 z = {0.f,0.f,0.f,0.f};
  floatx4 acc[4] = {z,z,z,z};
  for (int ks=0; ks<8; ++ks){
    ABu av; av.u4 = *(const uint4*)(C1 + (size_t)(sb0+ccol)*256 + ks*32 + q*8);
    for (int i=0;i<4;++i){
      ABu bf; bf.u4 = *(const uint4*)(w1p + ((size_t)((w*4+i)*8 + ks)*64 + L)*8);
      acc[i] = MFMA(av.v, bf.v, acc[i]);
    }
  }
  for (int i=0;i<4;++i){
    int icol = (w*4+i)*16 + ccol;
    float bia = b1[icol];
    for (int r=0;r<4;++r){
      int sb = sb0 + q*4 + r;
      P[(size_t)sb*256 + icol] = f2b(fmaxf(acc[i][r] + bia, 0.f));
    }
  }
}

// ---------------- persistent decoder ----------------

struct PArgs {
  const int* tlen;
  const float* ww; const float* wwb; const float* probb;
  const unsigned short* pmb; const unsigned short* encb;
  const unsigned short* W2f; const unsigned short* Wdecf;
  const unsigned short* W0p; const unsigned short* W1p;
  const float* b0p; const float* b1p;
  const unsigned short* P; const unsigned short* Woutp;
  unsigned short* xh0; unsigned short* xh1; unsigned short* acbf;
  unsigned int* bar; unsigned int* flag;
  float* dout;
};

__global__ __launch_bounds__(256, 1) void k_decoder(PArgs A)
{
  const int cu = blockIdx.x;
  const int tid = threadIdx.x;
  const int w = tid>>6, L = tid&63;
  const int ccol = L&15, q = L>>4;
  const int is_master = (cu == NBLKS-1);

  extern __shared__ char pool[];
  unsigned short* sW;
  unsigned short* sWOUT = nullptr;
  float* sGB; float* sCST; float* sBIAS;
  if (cu < 128){
    sW    = (unsigned short*)pool;                 // 98304 B
    sWOUT = (unsigned short*)(pool + 98304);       // 40960 B (cu 64..74)
    sGB   = (float*)(pool + 139264);
    sCST  = (float*)(pool + 147456);
    sBIAS = (float*)(pool + 149504);
  } else {
    sW    = (unsigned short*)pool;                 // 131072 B
    sGB   = (float*)(pool + 131072);
    sCST  = (float*)(pool + 139264);
    sBIAS = (float*)(pool + 141312);
  }

  __shared__ unsigned short s_ahi[240], s_alo[240];
  __shared__ unsigned short s_h0[1024];
  __shared__ float s_e[256];
  __shared__ float s_red[16];
  __shared__ float s_dp[128];
  __shared__ float s_ww[128];

  // ---- init: stage weights into LDS, zero state ----
  if (cu < 128){
    const unsigned short* src = A.W0p + (size_t)cu*48*2*512;
    for (int i = tid*8; i < 48*2*512; i += 2048)
      *(uint4*)(sW + i) = *(const uint4*)(src + i);
    if (cu >= 64 && cu < 75){
      const unsigned short* s2 = A.Woutp + (size_t)(cu-64)*40*512;
      for (int i = tid*8; i < 40*512; i += 2048)
        *(uint4*)(sWOUT + i) = *(const uint4*)(s2 + i);
    }
    if (tid < 32) sBIAS[tid] = A.b0p[cu*32 + tid];
  } else {
    const unsigned short* src = A.W1p + (size_t)(cu-128)*64*2*512;
    for (int i = tid*8; i < 64*2*512; i += 2048)
      *(uint4*)(sW + i) = *(const uint4*)(src + i);
    if (tid < 32) sBIAS[tid] = A.b1p[(cu-128)*32 + tid];
  }
  for (int i = tid; i < 512; i += 256) sCST[i] = 0.f;

  float accv = 0.f; int lenb = 0; float wwbv = 0.f;
  if (cu < 64) {
    lenb = A.tlen[cu];
    wwbv = A.wwb[0];
    float inv = 1.f / (float)lenb;
    for (int i = tid; i < 240; i += 256) {
      int t = i - 15;
      float v = (t >= 0 && t < 200 && t < lenb) ? inv : 0.f;
      unsigned short hi = f2b(v);
      s_ahi[i] = hi; s_alo[i] = f2b(v - b2f(hi));
    }
    if (tid < 200) accv = (tid < lenb) ? inv : 0.f;
    if (tid < 128) s_ww[tid] = A.ww[tid];
  }
  for (int i = tid; i < 512;  i += 256) A.xh0[cu*512  + i] = 0;
  for (int i = tid; i < 1024; i += 256) A.xh1[cu*1024 + i] = 0;

  unsigned int ep = 0;
  gbar(A.bar, A.flag, ++ep, is_master);

  for (int s = 0; s <= SS+1; ++s) {
    // ================= PHASE A =================
    if (cu < 64 && s < SS) {
      const int b = cu;
      const unsigned short* xh0r = A.xh0 + ((s+1)&1)*65536;
      // ---- stage h0_{s-1}(b) into LDS ----
      if (tid < 128) *(uint4*)(s_h0 + tid*8) = *(const uint4*)(xh0r + b*1024 + tid*8);
      __syncthreads();
      // ---- dp[h] = h0 @ Wdec^T via MFMA (m=0 row only) ----
      {
        floatx4 acc0 = {0.f,0.f,0.f,0.f}, acc1 = {0.f,0.f,0.f,0.f};
        for (int ks=0; ks<32; ++ks){
          ABu av;
          if (ccol == 0) av.u4 = *(const uint4*)(s_h0 + ks*32 + q*8);
          else { av.u4.x=0; av.u4.y=0; av.u4.z=0; av.u4.w=0; }
          ABu bf0, bf1;
          bf0.u4 = *(const uint4*)(A.Wdecf + ((size_t)((w*2+0)*32+ks)*64 + L)*8);
          bf1.u4 = *(const uint4*)(A.Wdecf + ((size_t)((w*2+1)*32+ks)*64 + L)*8);
          acc0 = MFMA(av.v, bf0.v, acc0);
          acc1 = MFMA(av.v, bf1.v, acc1);
        }
        if (L < 16){
          s_dp[(w*2+0)*16 + ccol] = acc0[0];
          s_dp[(w*2+1)*16 + ccol] = acc1[0];
        }
      }
      __syncthreads();
      // ---- conv (MFMA, hi/lo split) + scores ----
      {
        ABu w2f[8];
        for (int nt=0; nt<8; ++nt) w2f[nt].u4 = *(const uint4*)(A.W2f + (nt*64 + L)*8);
        const unsigned short* pmrow = A.pmb + (size_t)b*200*128;
        for (int mt = w; mt < 13; mt += 4) {
          ABu ahi, alo;
          int abase = mt*16 + ccol + q*8;
          for (int j=0;j<8;++j){ ahi.us[j] = s_ahi[abase+j]; alo.us[j] = s_alo[abase+j]; }
          floatx4 acc[8];
          for (int nt=0;nt<8;++nt){
            floatx4 zz = {0.f,0.f,0.f,0.f};
            zz = MFMA(ahi.v, w2f[nt].v, zz);
            zz = MFMA(alo.v, w2f[nt].v, zz);
            acc[nt] = zz;
          }
          for (int r=0;r<4;++r){
            int t = mt*16 + q*4 + r;
            float part = 0.f;
            if (t < 200) {
              for (int nt=0;nt<8;++nt){
                int h = nt*16 + ccol;
                float v = acc[nt][r] + b2f(pmrow[t*128+h]) + s_dp[h];
                part += s_ww[h] * tanhf_fast(v);
              }
            }
            part += __shfl_xor(part, 1);
            part += __shfl_xor(part, 2);
            part += __shfl_xor(part, 4);
            part += __shfl_xor(part, 8);
            if (t < 200 && ccol == 0)
              s_e[t] = (t < lenb) ? (part + wwbv) : -1e30f;
          }
        }
      }
      __syncthreads();
      // ---- softmax (wave shuffles, 2 barriers) + acc update ----
      {
        float v = (tid < 200) ? s_e[tid] : -1e30f;
        float m = v;
        for (int o=1;o<64;o<<=1) m = fmaxf(m, __shfl_xor(m, o));
        if (L == 0) s_red[w] = m;
        __syncthreads();
        m = fmaxf(fmaxf(s_red[0], s_red[1]), fmaxf(s_red[2], s_red[3]));
        float ex = (tid < 200) ? __expf(v - m) : 0.f;
        float sm = ex;
        for (int o=1;o<64;o<<=1) sm += __shfl_xor(sm, o);
        if (L == 0) s_red[8+w] = sm;
        __syncthreads();
        float inv = 1.f / (s_red[8]+s_red[9]+s_red[10]+s_red[11]);
        if (tid < 200){
          float aw = ex * inv;
          s_e[tid] = aw;
          A.dout[5184000 + (size_t)b*100000 + (size_t)s*200 + tid] = aw;
          accv = (s == 0) ? aw : (accv + aw);
          unsigned short hi = f2b(accv);
          s_ahi[15+tid] = hi; s_alo[15+tid] = f2b(accv - b2f(hi));
        }
      }
      __syncthreads();
      // ---- ac[c] = sum_t aw[t]*enc[b,t,c] ----
      {
        const unsigned short* er = A.encb + (size_t)b*200*256 + tid;
        float a0=0.f,a1=0.f,a2=0.f,a3=0.f;
        for (int t=0;t<200;t+=4){
          a0 += s_e[t  ]*b2f(er[(size_t)(t  )*256]);
          a1 += s_e[t+1]*b2f(er[(size_t)(t+1)*256]);
          a2 += s_e[t+2]*b2f(er[(size_t)(t+2)*256]);
          a3 += s_e[t+3]*b2f(er[(size_t)(t+3)*256]);
        }
        A.acbf[(s&3)*16384 + b*256 + tid] = f2b((a0+a1)+(a2+a3));
      }
    }
    if (cu >= 64 && cu < 75 && s >= 2) {
      // ---- output projection for step s-2 ----
      const int nt = cu - 64; const int s2 = s - 2;
      const unsigned short* segH  = A.xh1 + (size_t)(s2&3)*65536;
      const unsigned short* segAC = A.acbf + (s2&3)*16384;
      floatx4 acc = {0.f,0.f,0.f,0.f};
      int brow = w*16 + ccol;
      for (int ks=0; ks<40; ++ks){
        const unsigned short* ap = (ks < 32) ? (segH + (size_t)brow*1024 + ks*32 + q*8)
                                             : (segAC + (size_t)brow*256 + (ks-32)*32 + q*8);
        ABu av; av.u4 = *(const uint4*)ap;
        ABu bf; bf.u4 = *(const uint4*)(sWOUT + ((size_t)ks*64 + L)*8);
        acc = MFMA(av.v, bf.v, acc);
      }
      int j = nt*16 + ccol;
      for (int r=0;r<4;++r){
        int b = w*16 + q*4 + r;
        float val = acc[r];
        if (j < 160){
          int rr = j/80, cc2 = j%80;
          A.dout[(size_t)b*80000 + (size_t)cc2*1000 + s2*2 + rr] = val;
        } else if (j < 162){
          A.dout[5120000 + (size_t)b*1000 + s2*2 + (j-160)] = val + A.probb[j-160];
        }
      }
    }
    if (cu >= 128 && s >= 1 && s <= SS) {
      // ---- LSTM1 for step s-1 ----
      const int cp = cu - 128;
      const unsigned short* segA = A.xh0 + ((s+1)&1)*65536;
      const unsigned short* segB = A.xh1 + (size_t)((s-2)&3)*65536;
      floatx4 a0 = {0.f,0.f,0.f,0.f}, a1 = {0.f,0.f,0.f,0.f};
      int brow = w*16 + ccol;
      for (int ks=0; ks<64; ++ks){
        const unsigned short* ap = (ks < 32) ? (segA + (size_t)brow*1024 + ks*32 + q*8)
                                             : (segB + (size_t)brow*1024 + (ks-32)*32 + q*8);
        ABu av; av.u4 = *(const uint4*)ap;
        ABu b0f, b1f;
        b0f.u4 = *(const uint4*)(sW + ((size_t)(ks*2+0)*64 + L)*8);
        b1f.u4 = *(const uint4*)(sW + ((size_t)(ks*2+1)*64 + L)*8);
        a0 = MFMA(av.v, b0f.v, a0);
        a1 = MFMA(av.v, b1f.v, a1);
      }
      for (int r=0;r<4;++r){
        int bb = w*16 + q*4 + r;
        sGB[bb*32 + ccol]      = a0[r] + sBIAS[ccol];
        sGB[bb*32 + 16 + ccol] = a1[r] + sBIAS[16+ccol];
      }
      __syncthreads();
      unsigned short* xout = A.xh1 + (size_t)((s-1)&3)*65536;
      const unsigned short* hprev = segB;
      for (int rep=0;rep<2;++rep){
        int cell = tid + rep*256;
        int du = cell>>6, bb = cell&63;
        float gi=sGB[bb*32+du*4+0], gf=sGB[bb*32+du*4+1];
        float gg=sGB[bb*32+du*4+2], go=sGB[bb*32+du*4+3];
        float cprev = sCST[du*64+bb];
        float c2 = sigf(gf)*cprev + sigf(gi)*tanhf_fast(gg);
        float h2 = sigf(go)*tanhf_fast(c2);
        float cn = 0.1f*cprev + 0.9f*c2;
        float hp = b2f(hprev[(size_t)bb*1024 + cp*8 + du]);
        float hn = 0.1f*hp + 0.9f*h2;
        sCST[du*64+bb] = cn;
        xout[(size_t)bb*1024 + cp*8 + du] = f2b(hn);
      }
    }
    gbar(A.bar, A.flag, ++ep, is_master);
    // ================= PHASE B =================
    if (cu < 128 && s < SS) {
      // ---- LSTM0 for step s ----
      const unsigned short* segAC = A.acbf + (s&3)*16384;
      const unsigned short* segP  = A.P + (size_t)s*64*256;
      const unsigned short* segH  = A.xh0 + ((s+1)&1)*65536;
      floatx4 a0 = {0.f,0.f,0.f,0.f}, a1 = {0.f,0.f,0.f,0.f};
      int brow = w*16 + ccol;
      for (int ks=0; ks<48; ++ks){
        const unsigned short* ap;
        if (ks < 8)       ap = segAC + (size_t)brow*256  + ks*32 + q*8;
        else if (ks < 16) ap = segP  + (size_t)brow*256  + (ks-8)*32 + q*8;
        else              ap = segH  + (size_t)brow*1024 + (ks-16)*32 + q*8;
        ABu av; av.u4 = *(const uint4*)ap;
        ABu b0f, b1f;
        b0f.u4 = *(const uint4*)(sW + ((size_t)(ks*2+0)*64 + L)*8);
        b1f.u4 = *(const uint4*)(sW + ((size_t)(ks*2+1)*64 + L)*8);
        a0 = MFMA(av.v, b0f.v, a0);
        a1 = MFMA(av.v, b1f.v, a1);
      }
      for (int r=0;r<4;++r){
        int bb = w*16 + q*4 + r;
        sGB[bb*32 + ccol]      = a0[r] + sBIAS[ccol];
        sGB[bb*32 + 16 + ccol] = a1[r] + sBIAS[16+ccol];
      }
      __syncthreads();
      unsigned short* xout = A.xh0 + (s&1)*65536;
      const unsigned short* hprev = segH;
      for (int rep=0;rep<2;++rep){
        int cell = tid + rep*256;
        int du = cell>>6, bb = cell&63;
        float gi=sGB[bb*32+du*4+0], gf=sGB[bb*32+du*4+1];
        float gg=sGB[bb*32+du*4+2], go=sGB[bb*32+du*4+3];
        float cprev = sCST[du*64+bb];
        float c2 = sigf(gf)*cprev + sigf(gi)*tanhf_fast(gg);
        float h2 = sigf(go)*tanhf_fast(c2);
        float cn = 0.1f*cprev + 0.9f*c2;
        float hp = b2f(hprev[(size_t)bb*1024 + cu*8 + du]);
        float hn = 0.1f*hp + 0.9f*h2;
        sCST[du*64+bb] = cn;
        xout[(size_t)bb*1024 + cu*8 + du] = f2b(hn);
      }
    }
    gbar(A.bar, A.flag, ++ep, is_master);
  }
}

// ---------------- host launcher ----------------

extern "C" void kernel_launch(void* const* d_in, const int* in_sizes, int n_in,
                              void* d_out, int out_size, void* d_ws, size_t ws_size,
                              hipStream_t stream)
{
  const float* enc   = (const float*)d_in[0];
  const int*   tlen  = (const int*)d_in[1];
  const float* ftgt  = (const float*)d_in[2];
  const float* aew   = (const float*)d_in[3];
  const float* aeb   = (const float*)d_in[4];
  const float* adw   = (const float*)d_in[5];
  const float* aaw   = (const float*)d_in[6];
  const float* acw   = (const float*)d_in[7];
  const float* aww   = (const float*)d_in[8];
  const float* awb   = (const float*)d_in[9];
  const float* pw0   = (const float*)d_in[10];
  const float* pb0   = (const float*)d_in[11];
  const float* pw1   = (const float*)d_in[12];
  const float* pb1   = (const float*)d_in[13];
  const float* l0wih = (const float*)d_in[14];
  const float* l0whh = (const float*)d_in[15];
  const float* l0bih = (const float*)d_in[16];
  const float* l0bhh = (const float*)d_in[17];
  const float* l1wih = (const float*)d_in[18];
  const float* l1whh = (const float*)d_in[19];
  const float* l1bih = (const float*)d_in[20];
  const float* l1bhh = (const float*)d_in[21];
  const float* fow   = (const float*)d_in[22];
  const float* pow_  = (const float*)d_in[23];
  const float* pob   = (const float*)d_in[24];
  float* dout = (float*)d_out;

  char* ws = (char*)d_ws;
  size_t off = 0;
  auto alloc = [&](size_t bytes)->void*{
    void* p = (void*)(ws + off);
    off += (bytes + 255) & ~(size_t)255;
    return p;
  };

  unsigned short* pmb   = (unsigned short*)alloc((size_t)64*200*128*2);
  unsigned short* encb  = (unsigned short*)alloc((size_t)64*200*256*2);
  unsigned short* W2f   = (unsigned short*)alloc((size_t)8*64*8*2);
  unsigned short* Wdecf = (unsigned short*)alloc((size_t)8*32*64*8*2);
  unsigned short* W0p   = (unsigned short*)alloc((size_t)128*48*2*512*2);
  unsigned short* W1p   = (unsigned short*)alloc((size_t)128*64*2*512*2);
  float* b0p            = (float*)alloc((size_t)4096*4);
  float* b1p            = (float*)alloc((size_t)4096*4);
  unsigned short* w0pp  = (unsigned short*)alloc((size_t)16*5*512*2);
  unsigned short* w1pp  = (unsigned short*)alloc((size_t)16*8*512*2);
  unsigned short* C1    = (unsigned short*)alloc((size_t)32000*256*2);
  unsigned short* P     = (unsigned short*)alloc((size_t)32000*256*2);
  unsigned short* Woutp = (unsigned short*)alloc((size_t)11*40*512*2);
  unsigned short* xh0   = (unsigned short*)alloc((size_t)2*65536*2);
  unsigned short* xh1   = (unsigned short*)alloc((size_t)4*65536*2);
  unsigned short* acbf  = (unsigned short*)alloc((size_t)4*16384*2);
  unsigned int* bar     = (unsigned int*)alloc((size_t)NSLOT*128);
  unsigned int* flag    = (unsigned int*)alloc(256);

  hipMemsetAsync(bar, 0, (size_t)NSLOT*128, stream);
  hipMemsetAsync(flag, 0, 256, stream);

  k_pm     <<<6400, 256, 0, stream>>>(enc, aew, aeb, pmb);
  k_encb   <<<12800,256, 0, stream>>>(enc, encb);
  k_w2f    <<<1,    256, 0, stream>>>(aaw, acw, W2f);
  k_packgen<<<64,   256, 0, stream>>>(adw, Wdecf, 128, 1024);
  k_packlstm<<<1536,256, 0, stream>>>(l0wih, l0whh, W0p, 512, 48);
  k_packlstm<<<2048,256, 0, stream>>>(l1wih, l1whh, W1p, 1024, 64);
  k_bias   <<<16,   256, 0, stream>>>(l0bih, l0bhh, l1bih, l1bhh, b0p, b1p);
  k_packgen<<<20,   256, 0, stream>>>(pw0, w0pp, 256, 160);
  k_packgen<<<32,   256, 0, stream>>>(pw1, w1pp, 256, 256);
  k_woutp  <<<110,  256, 0, stream>>>(fow, pow_, Woutp);
  k_pre1   <<<2000, 256, 0, stream>>>(ftgt, w0pp, pb0, C1);
  k_pre2   <<<2000, 256, 0, stream>>>(C1, w1pp, pb1, P);

  PArgs A;
  A.tlen = tlen; A.ww = aww; A.wwb = awb; A.probb = pob;
  A.pmb = pmb; A.encb = encb; A.W2f = W2f; A.Wdecf = Wdecf;
  A.W0p = W0p; A.W1p = W1p; A.b0p = b0p; A.b1p = b1p;
  A.P = P; A.Woutp = Woutp;
  A.xh0 = xh0; A.xh1 = xh1; A.acbf = acbf;
  A.bar = bar; A.flag = flag; A.dout = dout;

  hipFuncSetAttribute((const void*)k_decoder,
                      hipFuncAttributeMaxDynamicSharedMemorySize, DYN_LDS);
  k_decoder<<<NBLKS, 256, DYN_LDS, stream>>>(A);
}

// Round 4
// 26333.102 us; speedup vs baseline: 8.5007x; 1.0022x over previous
//
#include <hip/hip_runtime.h>

#define SS 500
#define NBLKS 256
#define NSLOT 64
#define DYN_LDS 149632

typedef __bf16 bf16_t;
typedef bf16_t bf16x8 __attribute__((ext_vector_type(8)));
typedef float floatx4 __attribute__((ext_vector_type(4)));

union ABu { uint4 u4; bf16x8 v; unsigned short us[8]; };

#define MFMA(a,b,c) __builtin_amdgcn_mfma_f32_16x16x32_bf16((a),(b),(c),0,0,0)

__device__ __forceinline__ float b2f(unsigned short u){
  union { unsigned int ui; float f; } x; x.ui = ((unsigned int)u) << 16; return x.f;
}
__device__ __forceinline__ unsigned short f2b(float f){
  union { float f; unsigned int ui; } x; x.f = f;
  unsigned int r = x.ui + 0x7FFFu + ((x.ui >> 16) & 1u);
  return (unsigned short)(r >> 16);
}
__device__ __forceinline__ float sigf(float x){ return 1.f/(1.f + __expf(-x)); }
__device__ __forceinline__ float tanhf_fast(float x){
  x = fminf(fmaxf(x, -15.f), 15.f);
  float e = __expf(2.f*x);
  return (e - 1.f)/(e + 1.f);
}

// ---- grid barrier v4: spread arrivals + SPREAD release flags (64 lines) ----
// v3's single flag line was polled by 255 blocks at agent scope -> one LLC
// line serialized ~255 reqs/us -> ~23us/barrier. Now 4 pollers per line.
__device__ __forceinline__ void gbar(unsigned int* slots, unsigned int* flag,
                                     unsigned int ep, int is_master){
  __syncthreads();
  if (threadIdx.x == 0){
    __builtin_amdgcn_fence(__ATOMIC_RELEASE, "agent");   // one wbl2 per block
    __hip_atomic_fetch_add(&slots[(blockIdx.x & (NSLOT-1)) * 32], 1u,
                           __ATOMIC_RELAXED, __HIP_MEMORY_SCOPE_AGENT);
  }
  if (is_master){
    if (threadIdx.x < 64){
      for(;;){
        unsigned int v = __hip_atomic_load(&slots[threadIdx.x * 32],
                                           __ATOMIC_RELAXED, __HIP_MEMORY_SCOPE_AGENT);
        int t = (int)v;
        t += __shfl_xor(t, 1);  t += __shfl_xor(t, 2);  t += __shfl_xor(t, 4);
        t += __shfl_xor(t, 8);  t += __shfl_xor(t, 16); t += __shfl_xor(t, 32);
        if ((unsigned int)t >= ep * NBLKS) break;
        __builtin_amdgcn_s_sleep(1);
      }
      __builtin_amdgcn_fence(__ATOMIC_ACQUIRE, "agent"); // orders slot loads < flag stores
      __hip_atomic_store(&flag[threadIdx.x * 32], ep,
                         __ATOMIC_RELAXED, __HIP_MEMORY_SCOPE_AGENT);
    }
  } else {
    if (threadIdx.x == 0){
      unsigned int* myf = &flag[(blockIdx.x & (NSLOT-1)) * 32];
      while (__hip_atomic_load(myf, __ATOMIC_RELAXED, __HIP_MEMORY_SCOPE_AGENT) < ep)
        __builtin_amdgcn_s_sleep(2);
      __builtin_amdgcn_fence(__ATOMIC_ACQUIRE, "agent"); // one inv per block
    }
  }
  __syncthreads();
}

// ---------------- prep kernels ----------------

__global__ void k_pm(const float* __restrict__ enc, const float* __restrict__ ew,
                     const float* __restrict__ eb, unsigned short* __restrict__ pmb){
  int id = blockIdx.x*256 + threadIdx.x;
  if (id >= 64*200*128) return;
  int h = id & 127; int bt = id >> 7;
  const float* er = enc + (size_t)bt*256;
  const float* wr = ew + (size_t)h*256;
  float a0=eb[h], a1=0.f, a2=0.f, a3=0.f;
  for (int k=0;k<256;k+=4){
    a0 += er[k]*wr[k]; a1 += er[k+1]*wr[k+1]; a2 += er[k+2]*wr[k+2]; a3 += er[k+3]*wr[k+3];
  }
  pmb[id] = f2b((a0+a1)+(a2+a3));
}

__global__ void k_encb(const float* __restrict__ enc, unsigned short* __restrict__ encb){
  int id = blockIdx.x*256 + threadIdx.x;
  if (id >= 64*200*256) return;
  encb[id] = f2b(enc[id]);
}

__global__ void k_w2f(const float* __restrict__ attw, const float* __restrict__ convw,
                      unsigned short* __restrict__ w2f){
  __shared__ float s_w2[128*31];
  int tid = threadIdx.x;
  for (int i = tid; i < 128*31; i += 256){
    int h = i / 31, k = i % 31;
    float v = 0.f;
    for (int c=0;c<32;++c) v += attw[h*32+c]*convw[c*31+k];
    s_w2[i] = v;
  }
  __syncthreads();
  for (int i = tid; i < 512; i += 256){
    int nt = i >> 6, lane = i & 63;
    int h = nt*16 + (lane&15);
    for (int j=0;j<8;++j){
      int k = (lane>>4)*8 + j;
      w2f[(nt*64+lane)*8+j] = f2b(k < 31 ? s_w2[h*31+k] : 0.f);
    }
  }
}

__global__ void k_packlstm(const float* __restrict__ wih, const float* __restrict__ whh,
                           unsigned short* __restrict__ dst, int Kih, int NKS){
  int id = blockIdx.x*256 + threadIdx.x;
  if (id >= 128*NKS*64) return;
  int lane = id & 63; int t = id >> 6; int cu = t / NKS;
  for (int nt=0; nt<2; ++nt){
    int n = nt*16 + (lane&15);
    int du = n>>2, g = n&3;
    int row = g*1024 + cu*8 + du;
    for (int j=0;j<8;++j){
      int k = (t % NKS)*32 + ((lane>>4)*8) + j;
      float v = (k < Kih) ? wih[(size_t)row*Kih + k] : whh[(size_t)row*1024 + (k - Kih)];
      dst[((size_t)(t*2+nt)*64 + lane)*8 + j] = f2b(v);
    }
  }
}

__global__ void k_bias(const float* bi0,const float* bh0,const float* bi1,const float* bh1,
                       float* b0p, float* b1p){
  int id = blockIdx.x*256 + threadIdx.x;
  if (id >= 4096) return;
  int cu = id>>5, n = id&31, du = n>>2, g = n&3;
  int row = g*1024 + cu*8 + du;
  b0p[id] = bi0[row] + bh0[row];
  b1p[id] = bi1[row] + bh1[row];
}

__global__ void k_packgen(const float* __restrict__ src, unsigned short* __restrict__ dst,
                          int N, int K){
  int tot = (N/16)*(K/32)*64;
  int id = blockIdx.x*256 + threadIdx.x;
  if (id >= tot) return;
  int lane = id & 63; int t = id >> 6;
  int nks = K/32;
  int n = (t / nks)*16 + (lane&15);
  for (int j=0;j<8;++j){
    int k = (t % nks)*32 + (lane>>4)*8 + j;
    dst[((size_t)t*64 + lane)*8 + j] = f2b(src[(size_t)n*K + k]);
  }
}

__global__ void k_woutp(const float* __restrict__ fw, const float* __restrict__ pw,
                        unsigned short* __restrict__ dst){
  int id = blockIdx.x*256 + threadIdx.x;
  if (id >= 11*40*64) return;
  int lane = id & 63; int t = id >> 6;
  int n = (t/40)*16 + (lane&15);
  for (int j=0;j<8;++j){
    int k = (t%40)*32 + (lane>>4)*8 + j;
    float v = 0.f;
    if (n < 160) v = fw[(size_t)n*1280 + k];
    else if (n < 162) v = pw[(size_t)(n-160)*1280 + k];
    dst[((size_t)t*64 + lane)*8 + j] = f2b(v);
  }
}

__global__ void k_pre1(const float* __restrict__ ftgt, const unsigned short* __restrict__ w0p,
                       const float* __restrict__ b0, unsigned short* __restrict__ C1){
  int mt = blockIdx.x;
  int tid = threadIdx.x, w = tid>>6, L = tid&63, ccol = L&15, q = L>>4;
  int sb0 = mt*16; int s = sb0 >> 6; int b0r = sb0 & 63;
  floatx4 z = {0.f,0.f,0.f,0.f};
  floatx4 acc[4] = {z,z,z,z};
  for (int ks=0; ks<5; ++ks){
    ABu av;
    if (s == 0){ av.u4.x=0; av.u4.y=0; av.u4.z=0; av.u4.w=0; }
    else {
      int b = b0r + ccol;
      for (int j=0;j<8;++j){
        int jj = ks*32 + q*8 + j;
        av.us[j] = f2b(ftgt[(size_t)b*80000 + (size_t)(jj%80)*1000 + (size_t)(s-1)*2 + (jj/80)]);
      }
    }
    for (int i=0;i<4;++i){
      ABu bf; bf.u4 = *(const uint4*)(w0p + ((size_t)((w*4+i)*5 + ks)*64 + L)*8);
      acc[i] = MFMA(av.v, bf.v, acc[i]);
    }
  }
  for (int i=0;i<4;++i){
    int icol = (w*4+i)*16 + ccol;
    float bia = b0[icol];
    for (int r=0;r<4;++r){
      int sb = sb0 + q*4 + r;
      C1[(size_t)sb*256 + icol] = f2b(fmaxf(acc[i][r] + bia, 0.f));
    }
  }
}

__global__ void k_pre2(const unsigned short* __restrict__ C1, const unsigned short* __restrict__ w1p,
                       const float* __restrict__ b1, unsigned short* __restrict__ P){
  int mt = blockIdx.x;
  int tid = threadIdx.x, w = tid>>6, L = tid&63, ccol = L&15, q = L>>4;
  int sb0 = mt*16;
  floatx4 z = {0.f,0.f,0.f,0.f};
  floatx4 acc[4] = {z,z,z,z};
  for (int ks=0; ks<8; ++ks){
    ABu av; av.u4 = *(const uint4*)(C1 + (size_t)(sb0+ccol)*256 + ks*32 + q*8);
    for (int i=0;i<4;++i){
      ABu bf; bf.u4 = *(const uint4*)(w1p + ((size_t)((w*4+i)*8 + ks)*64 + L)*8);
      acc[i] = MFMA(av.v, bf.v, acc[i]);
    }
  }
  for (int i=0;i<4;++i){
    int icol = (w*4+i)*16 + ccol;
    float bia = b1[icol];
    for (int r=0;r<4;++r){
      int sb = sb0 + q*4 + r;
      P[(size_t)sb*256 + icol] = f2b(fmaxf(acc[i][r] + bia, 0.f));
    }
  }
}

// ---------------- persistent decoder ----------------

struct PArgs {
  const int* tlen;
  const float* ww; const float* wwb; const float* probb;
  const unsigned short* pmb; const unsigned short* encb;
  const unsigned short* W2f; const unsigned short* Wdecf;
  const unsigned short* W0p; const unsigned short* W1p;
  const float* b0p; const float* b1p;
  const unsigned short* P; const unsigned short* Woutp;
  unsigned short* xh0; unsigned short* xh1; unsigned short* acbf;
  unsigned int* bar; unsigned int* flag;
  float* dout;
};

__global__ __launch_bounds__(256, 1) void k_decoder(PArgs A)
{
  const int cu = blockIdx.x;
  const int tid = threadIdx.x;
  const int w = tid>>6, L = tid&63;
  const int ccol = L&15, q = L>>4;
  const int is_master = (cu == NBLKS-1);

  extern __shared__ char pool[];
  unsigned short* sW;
  unsigned short* sWOUT = nullptr;
  float* sGB; float* sCST; float* sBIAS;
  if (cu < 128){
    sW    = (unsigned short*)pool;                 // 98304 B
    sWOUT = (unsigned short*)(pool + 98304);       // 40960 B (cu 64..74)
    sGB   = (float*)(pool + 139264);
    sCST  = (float*)(pool + 147456);
    sBIAS = (float*)(pool + 149504);
  } else {
    sW    = (unsigned short*)pool;                 // 131072 B
    sGB   = (float*)(pool + 131072);
    sCST  = (float*)(pool + 139264);
    sBIAS = (float*)(pool + 141312);
  }

  __shared__ unsigned short s_ahi[240], s_alo[240];
  __shared__ unsigned short s_h0[1024];
  __shared__ float s_e[256];
  __shared__ float s_red[16];
  __shared__ float s_dp[128];
  __shared__ float s_ww[128];

  // ---- init: stage weights into LDS, zero state ----
  if (cu < 128){
    const unsigned short* src = A.W0p + (size_t)cu*48*2*512;
    for (int i = tid*8; i < 48*2*512; i += 2048)
      *(uint4*)(sW + i) = *(const uint4*)(src + i);
    if (cu >= 64 && cu < 75){
      const unsigned short* s2 = A.Woutp + (size_t)(cu-64)*40*512;
      for (int i = tid*8; i < 40*512; i += 2048)
        *(uint4*)(sWOUT + i) = *(const uint4*)(s2 + i);
    }
    if (tid < 32) sBIAS[tid] = A.b0p[cu*32 + tid];
  } else {
    const unsigned short* src = A.W1p + (size_t)(cu-128)*64*2*512;
    for (int i = tid*8; i < 64*2*512; i += 2048)
      *(uint4*)(sW + i) = *(const uint4*)(src + i);
    if (tid < 32) sBIAS[tid] = A.b1p[(cu-128)*32 + tid];
  }
  for (int i = tid; i < 512; i += 256) sCST[i] = 0.f;

  float accv = 0.f; int lenb = 0; float wwbv = 0.f;
  if (cu < 64) {
    lenb = A.tlen[cu];
    wwbv = A.wwb[0];
    float inv = 1.f / (float)lenb;
    for (int i = tid; i < 240; i += 256) {
      int t = i - 15;
      float v = (t >= 0 && t < 200 && t < lenb) ? inv : 0.f;
      unsigned short hi = f2b(v);
      s_ahi[i] = hi; s_alo[i] = f2b(v - b2f(hi));
    }
    if (tid < 200) accv = (tid < lenb) ? inv : 0.f;
    if (tid < 128) s_ww[tid] = A.ww[tid];
  }
  for (int i = tid; i < 512;  i += 256) A.xh0[cu*512  + i] = 0;
  for (int i = tid; i < 1024; i += 256) A.xh1[cu*1024 + i] = 0;

  unsigned int ep = 0;
  gbar(A.bar, A.flag, ++ep, is_master);

  for (int s = 0; s <= SS+1; ++s) {
    // ================= PHASE A =================
    if (cu < 64 && s < SS) {
      const int b = cu;
      const unsigned short* xh0r = A.xh0 + ((s+1)&1)*65536;
      // ---- stage h0_{s-1}(b) into LDS ----
      if (tid < 128) *(uint4*)(s_h0 + tid*8) = *(const uint4*)(xh0r + b*1024 + tid*8);
      __syncthreads();
      // ---- dp[h] = h0 @ Wdec^T via MFMA (m=0 row only) ----
      {
        floatx4 acc0 = {0.f,0.f,0.f,0.f}, acc1 = {0.f,0.f,0.f,0.f};
        for (int ks=0; ks<32; ++ks){
          ABu av;
          if (ccol == 0) av.u4 = *(const uint4*)(s_h0 + ks*32 + q*8);
          else { av.u4.x=0; av.u4.y=0; av.u4.z=0; av.u4.w=0; }
          ABu bf0, bf1;
          bf0.u4 = *(const uint4*)(A.Wdecf + ((size_t)((w*2+0)*32+ks)*64 + L)*8);
          bf1.u4 = *(const uint4*)(A.Wdecf + ((size_t)((w*2+1)*32+ks)*64 + L)*8);
          acc0 = MFMA(av.v, bf0.v, acc0);
          acc1 = MFMA(av.v, bf1.v, acc1);
        }
        if (L < 16){
          s_dp[(w*2+0)*16 + ccol] = acc0[0];
          s_dp[(w*2+1)*16 + ccol] = acc1[0];
        }
      }
      __syncthreads();
      // ---- conv (MFMA, hi/lo split) + scores ----
      {
        ABu w2f[8];
        for (int nt=0; nt<8; ++nt) w2f[nt].u4 = *(const uint4*)(A.W2f + (nt*64 + L)*8);
        const unsigned short* pmrow = A.pmb + (size_t)b*200*128;
        for (int mt = w; mt < 13; mt += 4) {
          ABu ahi, alo;
          int abase = mt*16 + ccol + q*8;
          for (int j=0;j<8;++j){ ahi.us[j] = s_ahi[abase+j]; alo.us[j] = s_alo[abase+j]; }
          floatx4 acc[8];
          for (int nt=0;nt<8;++nt){
            floatx4 zz = {0.f,0.f,0.f,0.f};
            zz = MFMA(ahi.v, w2f[nt].v, zz);
            zz = MFMA(alo.v, w2f[nt].v, zz);
            acc[nt] = zz;
          }
          for (int r=0;r<4;++r){
            int t = mt*16 + q*4 + r;
            float part = 0.f;
            if (t < 200) {
              for (int nt=0;nt<8;++nt){
                int h = nt*16 + ccol;
                float v = acc[nt][r] + b2f(pmrow[t*128+h]) + s_dp[h];
                part += s_ww[h] * tanhf_fast(v);
              }
            }
            part += __shfl_xor(part, 1);
            part += __shfl_xor(part, 2);
            part += __shfl_xor(part, 4);
            part += __shfl_xor(part, 8);
            if (t < 200 && ccol == 0)
              s_e[t] = (t < lenb) ? (part + wwbv) : -1e30f;
          }
        }
      }
      __syncthreads();
      // ---- softmax (wave shuffles) + acc update ----
      {
        float v = (tid < 200) ? s_e[tid] : -1e30f;
        float m = v;
        for (int o=1;o<64;o<<=1) m = fmaxf(m, __shfl_xor(m, o));
        if (L == 0) s_red[w] = m;
        __syncthreads();
        m = fmaxf(fmaxf(s_red[0], s_red[1]), fmaxf(s_red[2], s_red[3]));
        float ex = (tid < 200) ? __expf(v - m) : 0.f;
        float sm = ex;
        for (int o=1;o<64;o<<=1) sm += __shfl_xor(sm, o);
        if (L == 0) s_red[8+w] = sm;
        __syncthreads();
        float inv = 1.f / (s_red[8]+s_red[9]+s_red[10]+s_red[11]);
        if (tid < 200){
          float aw = ex * inv;
          s_e[tid] = aw;
          A.dout[5184000 + (size_t)b*100000 + (size_t)s*200 + tid] = aw;
          accv = (s == 0) ? aw : (accv + aw);
          unsigned short hi = f2b(accv);
          s_ahi[15+tid] = hi; s_alo[15+tid] = f2b(accv - b2f(hi));
        }
      }
      __syncthreads();
      // ---- ac[c] = sum_t aw[t]*enc[b,t,c] ----
      {
        const unsigned short* er = A.encb + (size_t)b*200*256 + tid;
        float a0=0.f,a1=0.f,a2=0.f,a3=0.f;
        for (int t=0;t<200;t+=4){
          a0 += s_e[t  ]*b2f(er[(size_t)(t  )*256]);
          a1 += s_e[t+1]*b2f(er[(size_t)(t+1)*256]);
          a2 += s_e[t+2]*b2f(er[(size_t)(t+2)*256]);
          a3 += s_e[t+3]*b2f(er[(size_t)(t+3)*256]);
        }
        A.acbf[(s&3)*16384 + b*256 + tid] = f2b((a0+a1)+(a2+a3));
      }
    }
    if (cu >= 64 && cu < 75 && s >= 2) {
      // ---- output projection for step s-2 ----
      const int nt = cu - 64; const int s2 = s - 2;
      const unsigned short* segH  = A.xh1 + (size_t)(s2&3)*65536;
      const unsigned short* segAC = A.acbf + (s2&3)*16384;
      floatx4 acc = {0.f,0.f,0.f,0.f};
      int brow = w*16 + ccol;
      for (int ks=0; ks<40; ++ks){
        const unsigned short* ap = (ks < 32) ? (segH + (size_t)brow*1024 + ks*32 + q*8)
                                             : (segAC + (size_t)brow*256 + (ks-32)*32 + q*8);
        ABu av; av.u4 = *(const uint4*)ap;
        ABu bf; bf.u4 = *(const uint4*)(sWOUT + ((size_t)ks*64 + L)*8);
        acc = MFMA(av.v, bf.v, acc);
      }
      int j = nt*16 + ccol;
      for (int r=0;r<4;++r){
        int b = w*16 + q*4 + r;
        float val = acc[r];
        if (j < 160){
          int rr = j/80, cc2 = j%80;
          A.dout[(size_t)b*80000 + (size_t)cc2*1000 + s2*2 + rr] = val;
        } else if (j < 162){
          A.dout[5120000 + (size_t)b*1000 + s2*2 + (j-160)] = val + A.probb[j-160];
        }
      }
    }
    if (cu >= 128 && s >= 1 && s <= SS) {
      // ---- LSTM1 for step s-1 ----
      const int cp = cu - 128;
      const unsigned short* segA = A.xh0 + ((s+1)&1)*65536;
      const unsigned short* segB = A.xh1 + (size_t)((s-2)&3)*65536;
      floatx4 a0 = {0.f,0.f,0.f,0.f}, a1 = {0.f,0.f,0.f,0.f};
      int brow = w*16 + ccol;
      for (int ks=0; ks<64; ++ks){
        const unsigned short* ap = (ks < 32) ? (segA + (size_t)brow*1024 + ks*32 + q*8)
                                             : (segB + (size_t)brow*1024 + (ks-32)*32 + q*8);
        ABu av; av.u4 = *(const uint4*)ap;
        ABu b0f, b1f;
        b0f.u4 = *(const uint4*)(sW + ((size_t)(ks*2+0)*64 + L)*8);
        b1f.u4 = *(const uint4*)(sW + ((size_t)(ks*2+1)*64 + L)*8);
        a0 = MFMA(av.v, b0f.v, a0);
        a1 = MFMA(av.v, b1f.v, a1);
      }
      for (int r=0;r<4;++r){
        int bb = w*16 + q*4 + r;
        sGB[bb*32 + ccol]      = a0[r] + sBIAS[ccol];
        sGB[bb*32 + 16 + ccol] = a1[r] + sBIAS[16+ccol];
      }
      __syncthreads();
      unsigned short* xout = A.xh1 + (size_t)((s-1)&3)*65536;
      const unsigned short* hprev = segB;
      for (int rep=0;rep<2;++rep){
        int cell = tid + rep*256;
        int du = cell>>6, bb = cell&63;
        float gi=sGB[bb*32+du*4+0], gf=sGB[bb*32+du*4+1];
        float gg=sGB[bb*32+du*4+2], go=sGB[bb*32+du*4+3];
        float cprev = sCST[du*64+bb];
        float c2 = sigf(gf)*cprev + sigf(gi)*tanhf_fast(gg);
        float h2 = sigf(go)*tanhf_fast(c2);
        float cn = 0.1f*cprev + 0.9f*c2;
        float hp = b2f(hprev[(size_t)bb*1024 + cp*8 + du]);
        float hn = 0.1f*hp + 0.9f*h2;
        sCST[du*64+bb] = cn;
        xout[(size_t)bb*1024 + cp*8 + du] = f2b(hn);
      }
    }
    gbar(A.bar, A.flag, ++ep, is_master);
    // ================= PHASE B =================
    if (cu < 128 && s < SS) {
      // ---- LSTM0 for step s ----
      const unsigned short* segAC = A.acbf + (s&3)*16384;
      const unsigned short* segP  = A.P + (size_t)s*64*256;
      const unsigned short* segH  = A.xh0 + ((s+1)&1)*65536;
      floatx4 a0 = {0.f,0.f,0.f,0.f}, a1 = {0.f,0.f,0.f,0.f};
      int brow = w*16 + ccol;
      for (int ks=0; ks<48; ++ks){
        const unsigned short* ap;
        if (ks < 8)       ap = segAC + (size_t)brow*256  + ks*32 + q*8;
        else if (ks < 16) ap = segP  + (size_t)brow*256  + (ks-8)*32 + q*8;
        else              ap = segH  + (size_t)brow*1024 + (ks-16)*32 + q*8;
        ABu av; av.u4 = *(const uint4*)ap;
        ABu b0f, b1f;
        b0f.u4 = *(const uint4*)(sW + ((size_t)(ks*2+0)*64 + L)*8);
        b1f.u4 = *(const uint4*)(sW + ((size_t)(ks*2+1)*64 + L)*8);
        a0 = MFMA(av.v, b0f.v, a0);
        a1 = MFMA(av.v, b1f.v, a1);
      }
      for (int r=0;r<4;++r){
        int bb = w*16 + q*4 + r;
        sGB[bb*32 + ccol]      = a0[r] + sBIAS[ccol];
        sGB[bb*32 + 16 + ccol] = a1[r] + sBIAS[16+ccol];
      }
      __syncthreads();
      unsigned short* xout = A.xh0 + (s&1)*65536;
      const unsigned short* hprev = segH;
      for (int rep=0;rep<2;++rep){
        int cell = tid + rep*256;
        int du = cell>>6, bb = cell&63;
        float gi=sGB[bb*32+du*4+0], gf=sGB[bb*32+du*4+1];
        float gg=sGB[bb*32+du*4+2], go=sGB[bb*32+du*4+3];
        float cprev = sCST[du*64+bb];
        float c2 = sigf(gf)*cprev + sigf(gi)*tanhf_fast(gg);
        float h2 = sigf(go)*tanhf_fast(c2);
        float cn = 0.1f*cprev + 0.9f*c2;
        float hp = b2f(hprev[(size_t)bb*1024 + cu*8 + du]);
        float hn = 0.1f*hp + 0.9f*h2;
        sCST[du*64+bb] = cn;
        xout[(size_t)bb*1024 + cu*8 + du] = f2b(hn);
      }
    }
    gbar(A.bar, A.flag, ++ep, is_master);
  }
}

// ---------------- host launcher ----------------

extern "C" void kernel_launch(void* const* d_in, const int* in_sizes, int n_in,
                              void* d_out, int out_size, void* d_ws, size_t ws_size,
                              hipStream_t stream)
{
  const float* enc   = (const float*)d_in[0];
  const int*   tlen  = (const int*)d_in[1];
  const float* ftgt  = (const float*)d_in[2];
  const float* aew   = (const float*)d_in[3];
  const float* aeb   = (const float*)d_in[4];
  const float* adw   = (const float*)d_in[5];
  const float* aaw   = (const float*)d_in[6];
  const float* acw   = (const float*)d_in[7];
  const float* aww   = (const float*)d_in[8];
  const float* awb   = (const float*)d_in[9];
  const float* pw0   = (const float*)d_in[10];
  const float* pb0   = (const float*)d_in[11];
  const float* pw1   = (const float*)d_in[12];
  const float* pb1   = (const float*)d_in[13];
  const float* l0wih = (const float*)d_in[14];
  const float* l0whh = (const float*)d_in[15];
  const float* l0bih = (const float*)d_in[16];
  const float* l0bhh = (const float*)d_in[17];
  const float* l1wih = (const float*)d_in[18];
  const float* l1whh = (const float*)d_in[19];
  const float* l1bih = (const float*)d_in[20];
  const float* l1bhh = (const float*)d_in[21];
  const float* fow   = (const float*)d_in[22];
  const float* pow_  = (const float*)d_in[23];
  const float* pob   = (const float*)d_in[24];
  float* dout = (float*)d_out;

  char* ws = (char*)d_ws;
  size_t off = 0;
  auto alloc = [&](size_t bytes)->void*{
    void* p = (void*)(ws + off);
    off += (bytes + 255) & ~(size_t)255;
    return p;
  };

  unsigned short* pmb   = (unsigned short*)alloc((size_t)64*200*128*2);
  unsigned short* encb  = (unsigned short*)alloc((size_t)64*200*256*2);
  unsigned short* W2f   = (unsigned short*)alloc((size_t)8*64*8*2);
  unsigned short* Wdecf = (unsigned short*)alloc((size_t)8*32*64*8*2);
  unsigned short* W0p   = (unsigned short*)alloc((size_t)128*48*2*512*2);
  unsigned short* W1p   = (unsigned short*)alloc((size_t)128*64*2*512*2);
  float* b0p            = (float*)alloc((size_t)4096*4);
  float* b1p            = (float*)alloc((size_t)4096*4);
  unsigned short* w0pp  = (unsigned short*)alloc((size_t)16*5*512*2);
  unsigned short* w1pp  = (unsigned short*)alloc((size_t)16*8*512*2);
  unsigned short* C1    = (unsigned short*)alloc((size_t)32000*256*2);
  unsigned short* P     = (unsigned short*)alloc((size_t)32000*256*2);
  unsigned short* Woutp = (unsigned short*)alloc((size_t)11*40*512*2);
  unsigned short* xh0   = (unsigned short*)alloc((size_t)2*65536*2);
  unsigned short* xh1   = (unsigned short*)alloc((size_t)4*65536*2);
  unsigned short* acbf  = (unsigned short*)alloc((size_t)4*16384*2);
  unsigned int* bar     = (unsigned int*)alloc((size_t)NSLOT*128);
  unsigned int* flag    = (unsigned int*)alloc((size_t)NSLOT*128);

  hipMemsetAsync(bar, 0, (size_t)NSLOT*128, stream);
  hipMemsetAsync(flag, 0, (size_t)NSLOT*128, stream);

  k_pm     <<<6400, 256, 0, stream>>>(enc, aew, aeb, pmb);
  k_encb   <<<12800,256, 0, stream>>>(enc, encb);
  k_w2f    <<<1,    256, 0, stream>>>(aaw, acw, W2f);
  k_packgen<<<64,   256, 0, stream>>>(adw, Wdecf, 128, 1024);
  k_packlstm<<<1536,256, 0, stream>>>(l0wih, l0whh, W0p, 512, 48);
  k_packlstm<<<2048,256, 0, stream>>>(l1wih, l1whh, W1p, 1024, 64);
  k_bias   <<<16,   256, 0, stream>>>(l0bih, l0bhh, l1bih, l1bhh, b0p, b1p);
  k_packgen<<<20,   256, 0, stream>>>(pw0, w0pp, 256, 160);
  k_packgen<<<32,   256, 0, stream>>>(pw1, w1pp, 256, 256);
  k_woutp  <<<110,  256, 0, stream>>>(fow, pow_, Woutp);
  k_pre1   <<<2000, 256, 0, stream>>>(ftgt, w0pp, pb0, C1);
  k_pre2   <<<2000, 256, 0, stream>>>(C1, w1pp, pb1, P);

  PArgs A;
  A.tlen = tlen; A.ww = aww; A.wwb = awb; A.probb = pob;
  A.pmb = pmb; A.encb = encb; A.W2f = W2f; A.Wdecf = Wdecf;
  A.W0p = W0p; A.W1p = W1p; A.b0p = b0p; A.b1p = b1p;
  A.P = P; A.Woutp = Woutp;
  A.xh0 = xh0; A.xh1 = xh1; A.acbf = acbf;
  A.bar = bar; A.flag = flag; A.dout = dout;

  hipFuncSetAttribute((const void*)k_decoder,
                      hipFuncAttributeMaxDynamicSharedMemorySize, DYN_LDS);
  k_decoder<<<NBLKS, 256, DYN_LDS, stream>>>(A);
}